// Round 1
// baseline (298.395 us; speedup 1.0000x reference)
//
#include <hip/hip_runtime.h>
#include <math.h>

#define NH_TOT 524288   // 4096*128
#define N_ATOM 4096
#define N_EDGE 65536

// ---------------------------------------------------------------------------
// U tables: U1[t][h] = sum_k emb_w[t][k]*emb2_w[h][k] ; U2 uses emb2_w[h][128+k]
// ---------------------------------------------------------------------------
__global__ __launch_bounds__(128) void k_u12(const float* __restrict__ emb_w,
                                             const float* __restrict__ emb2_w,
                                             float* __restrict__ U1,
                                             float* __restrict__ U2) {
    const int t = blockIdx.x, h = threadIdx.x;
    __shared__ float se[128];
    se[h] = emb_w[t * 128 + h];
    __syncthreads();
    float u1 = 0.f, u2 = 0.f;
    const float* row = emb2_w + h * 256;
#pragma unroll 8
    for (int k = 0; k < 128; k++) {
        u1 += se[k] * row[k];
        u2 += se[k] * row[128 + k];
    }
    U1[t * 128 + h] = u1;
    U2[t * 128 + h] = u2;
}

// ---------------------------------------------------------------------------
// CSR build
// ---------------------------------------------------------------------------
__global__ __launch_bounds__(256) void k_hist(const int* __restrict__ ei, int* __restrict__ cnt) {
    const int e = blockIdx.x * 256 + threadIdx.x;
    atomicAdd(&cnt[ei[e]], 1);
}

__global__ __launch_bounds__(256) void k_scan(const int* __restrict__ cnt, int* __restrict__ off) {
    __shared__ int s[256];
    const int t = threadIdx.x;
    int loc[16];
    int run = 0;
#pragma unroll
    for (int i = 0; i < 16; i++) { run += cnt[t * 16 + i]; loc[i] = run; }
    s[t] = run;
    __syncthreads();
    for (int d = 1; d < 256; d <<= 1) {
        const int add = (t >= d) ? s[t - d] : 0;
        __syncthreads();
        s[t] += add;
        __syncthreads();
    }
    const int base = s[t] - run;   // exclusive prefix of this thread's chunk
    if (t == 0) off[0] = 0;
#pragma unroll
    for (int i = 0; i < 16; i++) off[t * 16 + i + 1] = base + loc[i];
}

__global__ __launch_bounds__(256) void k_scatter(const int* __restrict__ ei,
                                                 const int* __restrict__ off,
                                                 int* __restrict__ cursor,
                                                 int* __restrict__ order) {
    const int e = blockIdx.x * 256 + threadIdx.x;
    const int s = ei[e];
    const int pos = off[s] + atomicAdd(&cursor[s], 1);
    order[pos] = e;
}

// ---------------------------------------------------------------------------
// Per-node edge accumulation + tensor_norm + LayerNorm(init)
// block = node (128 threads = channels). No atomics.
// acc planes: 0:i0 1:ax 2:ay 3:az 4:Mxx 5:Mxy 6:Mxz 7:Myy 8:Myz 9:Mzz
// ---------------------------------------------------------------------------
__global__ __launch_bounds__(128) void k_node(
    const float* __restrict__ edge_vec, const int* __restrict__ ei,
    const int* __restrict__ z, const int* __restrict__ off,
    const int* __restrict__ order, const float* __restrict__ U1,
    const float* __restrict__ U2, const float* __restrict__ emb2_b,
    const float* __restrict__ dp1_w, const float* __restrict__ dp1_b,
    const float* __restrict__ dp2_w, const float* __restrict__ dp2_b,
    const float* __restrict__ dp3_w, const float* __restrict__ dp3_b,
    const float* __restrict__ init_g, const float* __restrict__ init_b,
    float* __restrict__ acc, float* __restrict__ nrm) {
    const int n = blockIdx.x, h = threadIdx.x;
    const int beg = off[n], end = off[n + 1];

    float dp1r[32], dp2r[32], dp3r[32];
    {
        const float4* p1 = (const float4*)(dp1_w + h * 32);
        const float4* p2 = (const float4*)(dp2_w + h * 32);
        const float4* p3 = (const float4*)(dp3_w + h * 32);
#pragma unroll
        for (int j = 0; j < 8; j++) {
            ((float4*)dp1r)[j] = p1[j];
            ((float4*)dp2r)[j] = p2[j];
            ((float4*)dp3r)[j] = p3[j];
        }
    }
    const float u1h = U1[z[n] * 128 + h];
    const float bh = emb2_b[h];
    const float b1 = dp1_b[h], b2 = dp2_b[h], b3 = dp3_b[h];

    float aI = 0.f, ax = 0.f, ay = 0.f, az = 0.f;
    float mxx = 0.f, mxy = 0.f, mxz = 0.f, myy = 0.f, myz = 0.f, mzz = 0.f;

    __shared__ float s_vx[32], s_vy[32], s_vz[32], s_cut[32];
    __shared__ int s_u2[32];
    __shared__ float s_rbf[32][32];
    __shared__ float red[128];

    for (int base = beg; base < end; base += 32) {
        const int cnt = min(32, end - base);
        if (h < cnt) {
            const int e = order[base + h];
            const float evx = edge_vec[3 * e + 0];
            const float evy = edge_vec[3 * e + 1];
            const float evz = edge_vec[3 * e + 2];
            const float d = sqrtf(evx * evx + evy * evy + evz * evz);
            const float inv = 1.0f / d;
            s_vx[h] = evx * inv; s_vy[h] = evy * inv; s_vz[h] = evz * inv;
            const float cut = (d < 4.5f) ? 0.5f * (cosf(0.6981317007977318f * d) + 1.0f) : 0.0f;
            s_cut[h] = cut;
            s_u2[h] = z[ei[N_EDGE + e]] * 128;
            const float expd = expf(-1.1111111111111112f * d);
            const float m0 = 0.011108996538242306f;
            const float dm = (1.0f - m0) * (1.0f / 31.0f);
            const float tb = 0.0625f * (1.0f - m0);
            const float beta = 1.0f / (tb * tb);
#pragma unroll
            for (int r = 0; r < 32; r++) {
                const float df = expd - (m0 + (float)r * dm);
                s_rbf[h][r] = cut * expf(-beta * df * df);
            }
        }
        __syncthreads();
#pragma unroll 1
        for (int i = 0; i < cnt; i++) {
            const float c = s_cut[i] * (u1h + U2[s_u2[i] + h] + bh);
            float p1 = b1, p2 = b2, p3 = b3;
            const float4* rp = (const float4*)s_rbf[i];
#pragma unroll
            for (int r4 = 0; r4 < 8; r4++) {
                const float4 rv = rp[r4];
                p1 += rv.x * dp1r[r4 * 4 + 0]; p2 += rv.x * dp2r[r4 * 4 + 0]; p3 += rv.x * dp3r[r4 * 4 + 0];
                p1 += rv.y * dp1r[r4 * 4 + 1]; p2 += rv.y * dp2r[r4 * 4 + 1]; p3 += rv.y * dp3r[r4 * 4 + 1];
                p1 += rv.z * dp1r[r4 * 4 + 2]; p2 += rv.z * dp2r[r4 * 4 + 2]; p3 += rv.z * dp3r[r4 * 4 + 2];
                p1 += rv.w * dp1r[r4 * 4 + 3]; p2 += rv.w * dp2r[r4 * 4 + 3]; p3 += rv.w * dp3r[r4 * 4 + 3];
            }
            const float w1 = p1 * c, w2 = p2 * c, w3 = p3 * c;
            const float vx = s_vx[i], vy = s_vy[i], vz = s_vz[i];
            aI += w1;
            ax += w2 * vx; ay += w2 * vy; az += w2 * vz;
            mxx += w3 * vx * vx; mxy += w3 * vx * vy; mxz += w3 * vx * vz;
            myy += w3 * vy * vy; myz += w3 * vy * vz; mzz += w3 * vz * vz;
        }
        __syncthreads();
    }

    // tensor_norm: || i0*I + skew(a) + (M - tr/3 I) ||_F^2
    const float tr3 = (mxx + myy + mzz) * (1.0f / 3.0f);
    const float t00 = aI + mxx - tr3;
    const float t11 = aI + myy - tr3;
    const float t22 = aI + mzz - tr3;
    const float tn = t00 * t00 + t11 * t11 + t22 * t22 +
                     2.0f * (mxy * mxy + az * az + mxz * mxz + ay * ay + myz * myz + ax * ax);

    // LayerNorm over 128 channels
    red[h] = tn;
    __syncthreads();
    for (int s = 64; s > 0; s >>= 1) { if (h < s) red[h] += red[h + s]; __syncthreads(); }
    const float mu = red[0] * (1.0f / 128.0f);
    __syncthreads();
    const float dv = tn - mu;
    red[h] = dv * dv;
    __syncthreads();
    for (int s = 64; s > 0; s >>= 1) { if (h < s) red[h] += red[h + s]; __syncthreads(); }
    const float var = red[0] * (1.0f / 128.0f);

    const int idx = n * 128 + h;
    nrm[idx] = dv * rsqrtf(var + 1e-5f) * init_g[h] + init_b[h];
    acc[idx] = aI;
    acc[NH_TOT + idx] = ax;  acc[2 * NH_TOT + idx] = ay;  acc[3 * NH_TOT + idx] = az;
    acc[4 * NH_TOT + idx] = mxx; acc[5 * NH_TOT + idx] = mxy; acc[6 * NH_TOT + idx] = mxz;
    acc[7 * NH_TOT + idx] = myy; acc[8 * NH_TOT + idx] = myz; acc[9 * NH_TOT + idx] = mzz;
}

// ---------------------------------------------------------------------------
// Generic fp32 GEMM: C(N x M) = act(A(N x K) @ B(M x K)^T + bias)
// 64x64 tile, 256 threads, 4x4 register blocking. act: 0 none, 1 silu
// ---------------------------------------------------------------------------
__device__ __forceinline__ void gemm_body(const float* __restrict__ A, const float* __restrict__ B,
                                          const float* __restrict__ bias, float* __restrict__ C,
                                          int K, int M, int act,
                                          float As[16][68], float Bs[16][68]) {
    const int tid = threadIdx.x;
    const int tx = tid & 15, ty = tid >> 4;
    const int n0 = blockIdx.x * 64, m0 = blockIdx.y * 64;
    const int lr = tid >> 2;
    const int lk = (tid & 3) * 4;
    float accv[4][4] = {};

    for (int kc = 0; kc < K; kc += 16) {
        const float4 a4 = *(const float4*)(A + (size_t)(n0 + lr) * K + kc + lk);
        const float4 b4 = *(const float4*)(B + (size_t)(m0 + lr) * K + kc + lk);
        __syncthreads();
        As[lk + 0][lr] = a4.x; As[lk + 1][lr] = a4.y; As[lk + 2][lr] = a4.z; As[lk + 3][lr] = a4.w;
        Bs[lk + 0][lr] = b4.x; Bs[lk + 1][lr] = b4.y; Bs[lk + 2][lr] = b4.z; Bs[lk + 3][lr] = b4.w;
        __syncthreads();
#pragma unroll
        for (int kk = 0; kk < 16; kk++) {
            const float4 av = *(const float4*)&As[kk][ty * 4];
            const float4 bv = *(const float4*)&Bs[kk][tx * 4];
            accv[0][0] += av.x * bv.x; accv[0][1] += av.x * bv.y; accv[0][2] += av.x * bv.z; accv[0][3] += av.x * bv.w;
            accv[1][0] += av.y * bv.x; accv[1][1] += av.y * bv.y; accv[1][2] += av.y * bv.z; accv[1][3] += av.y * bv.w;
            accv[2][0] += av.z * bv.x; accv[2][1] += av.z * bv.y; accv[2][2] += av.z * bv.z; accv[2][3] += av.z * bv.w;
            accv[3][0] += av.w * bv.x; accv[3][1] += av.w * bv.y; accv[3][2] += av.w * bv.z; accv[3][3] += av.w * bv.w;
        }
    }
#pragma unroll
    for (int i = 0; i < 4; i++) {
        float o[4];
#pragma unroll
        for (int j = 0; j < 4; j++) {
            float v = accv[i][j];
            if (bias) v += bias[m0 + tx * 4 + j];
            if (act) v = v / (1.0f + expf(-v));
            o[j] = v;
        }
        *(float4*)(C + (size_t)(n0 + ty * 4 + i) * M + m0 + tx * 4) = make_float4(o[0], o[1], o[2], o[3]);
    }
}

__global__ __launch_bounds__(256) void k_gemm(const float* __restrict__ A, const float* __restrict__ B,
                                              const float* __restrict__ bias, float* __restrict__ C,
                                              int K, int M, int act) {
    __shared__ float As[16][68], Bs[16][68];
    gemm_body(A, B, bias, C, K, M, act, As, Bs);
}

__global__ __launch_bounds__(256) void k_mix(const float* __restrict__ acc,
                                             const float* __restrict__ lt0,
                                             const float* __restrict__ lt1,
                                             const float* __restrict__ lt2,
                                             float* __restrict__ out10) {
    __shared__ float As[16][68], Bs[16][68];
    const int c = blockIdx.z;
    const float* B = (c == 0) ? lt0 : ((c < 4) ? lt1 : lt2);
    gemm_body(acc + (size_t)c * NH_TOT, B, nullptr, out10 + (size_t)c * NH_TOT, 128, 128, 0, As, Bs);
}

// ---------------------------------------------------------------------------
// Combine mixed planes with per-channel gates -> x (N x 384)
// ---------------------------------------------------------------------------
__global__ __launch_bounds__(256) void k_combine(const float* __restrict__ out10,
                                                 const float* __restrict__ scal,
                                                 float* __restrict__ x) {
    const int idx = blockIdx.x * 256 + threadIdx.x;
    const int n = idx >> 7, g = idx & 127;
    const float i1 = out10[idx];
    const float a1x = out10[NH_TOT + idx], a1y = out10[2 * NH_TOT + idx], a1z = out10[3 * NH_TOT + idx];
    const float sxx = out10[4 * NH_TOT + idx], sxy = out10[5 * NH_TOT + idx], sxz = out10[6 * NH_TOT + idx];
    const float syy = out10[7 * NH_TOT + idx], syz = out10[8 * NH_TOT + idx], szz = out10[9 * NH_TOT + idx];
    const float s0 = scal[n * 384 + 3 * g + 0];
    const float s1 = scal[n * 384 + 3 * g + 1];
    const float s2 = scal[n * 384 + 3 * g + 2];
    const float x0 = 3.0f * i1 * i1 * s0 * s0;
    const float x1 = 2.0f * (a1x * a1x + a1y * a1y + a1z * a1z) * s1 * s1;
    const float tr3 = (sxx + syy + szz) * (1.0f / 3.0f);
    const float d0 = sxx - tr3, d1 = syy - tr3, d2 = szz - tr3;
    const float x2 = (d0 * d0 + d1 * d1 + d2 * d2 + 2.0f * (sxy * sxy + sxz * sxz + syz * syz)) * s2 * s2;
    x[n * 384 + g] = x0;
    x[n * 384 + 128 + g] = x1;
    x[n * 384 + 256 + g] = x2;
}

// ---------------------------------------------------------------------------
// LayerNorm over 384 (in place)
// ---------------------------------------------------------------------------
__global__ __launch_bounds__(128) void k_ln384(float* __restrict__ x, const float* __restrict__ g,
                                               const float* __restrict__ b) {
    const int n = blockIdx.x, t = threadIdx.x;
    __shared__ float red[128];
    const float e0 = x[n * 384 + t], e1 = x[n * 384 + 128 + t], e2 = x[n * 384 + 256 + t];
    red[t] = e0 + e1 + e2;
    __syncthreads();
    for (int s = 64; s > 0; s >>= 1) { if (t < s) red[t] += red[t + s]; __syncthreads(); }
    const float mu = red[0] * (1.0f / 384.0f);
    __syncthreads();
    const float d0 = e0 - mu, d1 = e1 - mu, d2 = e2 - mu;
    red[t] = d0 * d0 + d1 * d1 + d2 * d2;
    __syncthreads();
    for (int s = 64; s > 0; s >>= 1) { if (t < s) red[t] += red[t + s]; __syncthreads(); }
    const float rs = rsqrtf(red[0] * (1.0f / 384.0f) + 1e-5f);
    __syncthreads();
    x[n * 384 + t]       = d0 * rs * g[t]       + b[t];
    x[n * 384 + 128 + t] = d1 * rs * g[128 + t] + b[128 + t];
    x[n * 384 + 256 + t] = d2 * rs * g[256 + t] + b[256 + t];
}

// ---------------------------------------------------------------------------
// Final MLP tail: s2 = silu(s1)@ol1^T+b (s1s already silu'd), silu, dot ol2
// ---------------------------------------------------------------------------
__global__ __launch_bounds__(64) void k_final(const float* __restrict__ s1s,
                                              const float* __restrict__ ol1_w,
                                              const float* __restrict__ ol1_b,
                                              const float* __restrict__ ol2_w,
                                              const float* __restrict__ ol2_b,
                                              float* __restrict__ out) {
    const int n = blockIdx.x, j = threadIdx.x;
    __shared__ float srow[128];
    srow[j] = s1s[n * 128 + j];
    srow[j + 64] = s1s[n * 128 + 64 + j];
    __syncthreads();
    float a = ol1_b[j];
    const float4* wr = (const float4*)(ol1_w + j * 128);
#pragma unroll
    for (int k4 = 0; k4 < 32; k4++) {
        const float4 w4 = wr[k4];
        a += srow[k4 * 4 + 0] * w4.x + srow[k4 * 4 + 1] * w4.y +
             srow[k4 * 4 + 2] * w4.z + srow[k4 * 4 + 3] * w4.w;
    }
    float v = a / (1.0f + expf(-a)) * ol2_w[j];
    for (int sft = 32; sft > 0; sft >>= 1) v += __shfl_down(v, sft, 64);
    if (j == 0) out[n] = v + ol2_b[0];
}

// ---------------------------------------------------------------------------
extern "C" void kernel_launch(void* const* d_in, const int* in_sizes, int n_in,
                              void* d_out, int out_size, void* d_ws, size_t ws_size,
                              hipStream_t stream) {
    (void)in_sizes; (void)n_in; (void)out_size; (void)ws_size;
    const float* edge_vec = (const float*)d_in[0];
    const float* emb_w   = (const float*)d_in[1];
    const float* emb2_w  = (const float*)d_in[2];
    const float* emb2_b  = (const float*)d_in[3];
    const float* dp1_w   = (const float*)d_in[4];
    const float* dp1_b   = (const float*)d_in[5];
    const float* dp2_w   = (const float*)d_in[6];
    const float* dp2_b   = (const float*)d_in[7];
    const float* dp3_w   = (const float*)d_in[8];
    const float* dp3_b   = (const float*)d_in[9];
    const float* lt0_w   = (const float*)d_in[10];
    const float* lt1_w   = (const float*)d_in[11];
    const float* lt2_w   = (const float*)d_in[12];
    const float* ls0_w   = (const float*)d_in[13];
    const float* ls0_b   = (const float*)d_in[14];
    const float* ls1_w   = (const float*)d_in[15];
    const float* ls1_b   = (const float*)d_in[16];
    const float* init_g  = (const float*)d_in[17];
    const float* init_b  = (const float*)d_in[18];
    const float* lin_w   = (const float*)d_in[19];
    const float* lin_b   = (const float*)d_in[20];
    const float* outn_g  = (const float*)d_in[21];
    const float* outn_b  = (const float*)d_in[22];
    const float* ol1_w   = (const float*)d_in[23];
    const float* ol1_b   = (const float*)d_in[24];
    const float* ol2_w   = (const float*)d_in[25];
    const float* ol2_b   = (const float*)d_in[26];
    const int* z  = (const int*)d_in[27];
    const int* ei = (const int*)d_in[28];
    float* out = (float*)d_out;

    char* w = (char*)d_ws;
    int* cnt     = (int*)(w);             // 16 KB
    int* cursor  = (int*)(w + 16384);     // 16 KB
    int* off     = (int*)(w + 32768);     // 4097 ints
    int* order   = (int*)(w + 49408);     // 256 KB
    float* U1    = (float*)(w + 311552);  // 64 KB
    float* U2    = (float*)(w + 377088);  // 64 KB
    float* acc   = (float*)(w + 442624);        // 20 MB (10 planes) -- later aliased as x
    float* nrm   = (float*)(w + 21414144);      // 2 MB -- later aliased as s1s
    float* hbuf  = (float*)(w + 23511296);      // 4 MB
    float* scal  = (float*)(w + 27705600);      // 6 MB
    float* out10 = (float*)(w + 33997056);      // 20 MB   (end ~55 MB)
    float* xbuf = acc;   // acc dead after k_mix
    float* s1s  = nrm;   // nrm dead after first GEMM

    hipMemsetAsync(w, 0, 32768, stream);  // cnt + cursor
    k_u12<<<dim3(128), dim3(128), 0, stream>>>(emb_w, emb2_w, U1, U2);
    k_hist<<<dim3(256), dim3(256), 0, stream>>>(ei, cnt);
    k_scan<<<dim3(1), dim3(256), 0, stream>>>(cnt, off);
    k_scatter<<<dim3(256), dim3(256), 0, stream>>>(ei, off, cursor, order);
    k_node<<<dim3(4096), dim3(128), 0, stream>>>(edge_vec, ei, z, off, order, U1, U2, emb2_b,
                                                 dp1_w, dp1_b, dp2_w, dp2_b, dp3_w, dp3_b,
                                                 init_g, init_b, acc, nrm);
    k_gemm<<<dim3(64, 4), dim3(256), 0, stream>>>(nrm, ls0_w, ls0_b, hbuf, 128, 256, 1);
    k_gemm<<<dim3(64, 6), dim3(256), 0, stream>>>(hbuf, ls1_w, ls1_b, scal, 256, 384, 1);
    k_mix<<<dim3(64, 2, 10), dim3(256), 0, stream>>>(acc, lt0_w, lt1_w, lt2_w, out10);
    k_combine<<<dim3(2048), dim3(256), 0, stream>>>(out10, scal, xbuf);
    k_ln384<<<dim3(4096), dim3(128), 0, stream>>>(xbuf, outn_g, outn_b);
    k_gemm<<<dim3(64, 2), dim3(256), 0, stream>>>(xbuf, lin_w, lin_b, s1s, 384, 128, 1);
    k_final<<<dim3(4096), dim3(64), 0, stream>>>(s1s, ol1_w, ol1_b, ol2_w, ol2_b, out);
}

// Round 2
// 296.099 us; speedup vs baseline: 1.0078x; 1.0078x over previous
//
#include <hip/hip_runtime.h>
#include <math.h>

#define NH_TOT 524288   // 4096*128
#define N_ATOM 4096
#define N_EDGE 65536

// ---------------------------------------------------------------------------
// U tables: U1[t][h] = sum_k emb_w[t][k]*emb2_w[h][k] ; U2 uses emb2_w[h][128+k]
// ---------------------------------------------------------------------------
__global__ __launch_bounds__(128) void k_u12(const float* __restrict__ emb_w,
                                             const float* __restrict__ emb2_w,
                                             float* __restrict__ U1,
                                             float* __restrict__ U2) {
    const int t = blockIdx.x, h = threadIdx.x;
    __shared__ float se[128];
    se[h] = emb_w[t * 128 + h];
    __syncthreads();
    float u1 = 0.f, u2 = 0.f;
    const float* row = emb2_w + h * 256;
#pragma unroll 8
    for (int k = 0; k < 128; k++) {
        u1 += se[k] * row[k];
        u2 += se[k] * row[128 + k];
    }
    U1[t * 128 + h] = u1;
    U2[t * 128 + h] = u2;
}

// ---------------------------------------------------------------------------
// CSR build
// ---------------------------------------------------------------------------
__global__ __launch_bounds__(256) void k_hist(const int* __restrict__ ei, int* __restrict__ cnt) {
    const int e = blockIdx.x * 256 + threadIdx.x;
    atomicAdd(&cnt[ei[e]], 1);
}

__global__ __launch_bounds__(256) void k_scan(const int* __restrict__ cnt, int* __restrict__ off) {
    __shared__ int s[256];
    const int t = threadIdx.x;
    int loc[16];
    int run = 0;
#pragma unroll
    for (int i = 0; i < 16; i++) { run += cnt[t * 16 + i]; loc[i] = run; }
    s[t] = run;
    __syncthreads();
    for (int d = 1; d < 256; d <<= 1) {
        const int add = (t >= d) ? s[t - d] : 0;
        __syncthreads();
        s[t] += add;
        __syncthreads();
    }
    const int base = s[t] - run;   // exclusive prefix of this thread's chunk
    if (t == 0) off[0] = 0;
#pragma unroll
    for (int i = 0; i < 16; i++) off[t * 16 + i + 1] = base + loc[i];
}

__global__ __launch_bounds__(256) void k_scatter(const int* __restrict__ ei,
                                                 const int* __restrict__ off,
                                                 int* __restrict__ cursor,
                                                 int* __restrict__ order) {
    const int e = blockIdx.x * 256 + threadIdx.x;
    const int s = ei[e];
    const int pos = off[s] + atomicAdd(&cursor[s], 1);
    order[pos] = e;
}

// ---------------------------------------------------------------------------
// Edge precompute IN SORTED ORDER: position i holds edge order[i].
// rbf (cut-premultiplied, E x 32), geom = {vx,vy,vz,cut}, u2off = z[dst]*128
// ---------------------------------------------------------------------------
__global__ __launch_bounds__(256) void k_edge(const float* __restrict__ edge_vec,
                                              const int* __restrict__ ei,
                                              const int* __restrict__ z,
                                              const int* __restrict__ order,
                                              float* __restrict__ rbf_s,
                                              float4* __restrict__ geom,
                                              int* __restrict__ u2off) {
    const int i = blockIdx.x * 256 + threadIdx.x;
    const int e = order[i];
    const float evx = edge_vec[3 * e + 0];
    const float evy = edge_vec[3 * e + 1];
    const float evz = edge_vec[3 * e + 2];
    const float d = sqrtf(evx * evx + evy * evy + evz * evz);
    const float inv = 1.0f / d;
    const float cut = (d < 4.5f) ? 0.5f * (cosf(0.6981317007977318f * d) + 1.0f) : 0.0f;
    geom[i] = make_float4(evx * inv, evy * inv, evz * inv, cut);
    u2off[i] = z[ei[N_EDGE + e]] << 7;

    const float expd = expf(-1.1111111111111112f * d);
    const float m0 = 0.011108996538242306f;
    const float dm = (1.0f - m0) * (1.0f / 31.0f);
    const float tb = 0.0625f * (1.0f - m0);
    const float beta = 1.0f / (tb * tb);
    float rv[32];
#pragma unroll
    for (int r = 0; r < 32; r++) {
        const float df = expd - (m0 + (float)r * dm);
        rv[r] = cut * expf(-beta * df * df);
    }
    float4* dst = (float4*)(rbf_s + (size_t)i * 32);
#pragma unroll
    for (int j = 0; j < 8; j++) dst[j] = ((const float4*)rv)[j];
}

// ---------------------------------------------------------------------------
// Per-node accumulation + tensor_norm + LayerNorm(init).
// Block = 2 nodes sequentially, 128 threads (=channels). No barriers in the
// edge loop: rbf/geom are wave-broadcast global reads (L2-resident).
// acc planes: 0:i0 1:ax 2:ay 3:az 4:Mxx 5:Mxy 6:Mxz 7:Myy 8:Myz 9:Mzz
// ---------------------------------------------------------------------------
__global__ __launch_bounds__(128) void k_node(
    const int* __restrict__ z, const int* __restrict__ off,
    const float* __restrict__ rbf_s, const float4* __restrict__ geom,
    const int* __restrict__ u2off,
    const float* __restrict__ U1, const float* __restrict__ U2,
    const float* __restrict__ emb2_b,
    const float* __restrict__ dp1_w, const float* __restrict__ dp1_b,
    const float* __restrict__ dp2_w, const float* __restrict__ dp2_b,
    const float* __restrict__ dp3_w, const float* __restrict__ dp3_b,
    const float* __restrict__ init_g, const float* __restrict__ init_b,
    float* __restrict__ acc, float* __restrict__ nrm) {
    const int h = threadIdx.x;

    float dp1r[32], dp2r[32], dp3r[32];
    {
        const float4* p1 = (const float4*)(dp1_w + h * 32);
        const float4* p2 = (const float4*)(dp2_w + h * 32);
        const float4* p3 = (const float4*)(dp3_w + h * 32);
#pragma unroll
        for (int j = 0; j < 8; j++) {
            ((float4*)dp1r)[j] = p1[j];
            ((float4*)dp2r)[j] = p2[j];
            ((float4*)dp3r)[j] = p3[j];
        }
    }
    const float bh = emb2_b[h];
    const float b1 = dp1_b[h], b2 = dp2_b[h], b3 = dp3_b[h];
    const float gih = init_g[h], bih = init_b[h];

    __shared__ float red[128];

    for (int nn = 0; nn < 2; nn++) {
        const int n = blockIdx.x * 2 + nn;
        const float u1h = U1[(z[n] << 7) + h];
        const int beg = off[n], end = off[n + 1];

        float aI = 0.f, ax = 0.f, ay = 0.f, az = 0.f;
        float mxx = 0.f, mxy = 0.f, mxz = 0.f, myy = 0.f, myz = 0.f, mzz = 0.f;

#pragma unroll 2
        for (int i = beg; i < end; i++) {
            const float4 g = geom[i];
            const float u2v = U2[u2off[i] + h];
            const float c = g.w * (u1h + u2v + bh);
            float p1 = b1, p2 = b2, p3 = b3;
            const float4* rp = (const float4*)(rbf_s + (size_t)i * 32);
#pragma unroll
            for (int r4 = 0; r4 < 8; r4++) {
                const float4 rv = rp[r4];
                p1 += rv.x * dp1r[r4 * 4 + 0]; p2 += rv.x * dp2r[r4 * 4 + 0]; p3 += rv.x * dp3r[r4 * 4 + 0];
                p1 += rv.y * dp1r[r4 * 4 + 1]; p2 += rv.y * dp2r[r4 * 4 + 1]; p3 += rv.y * dp3r[r4 * 4 + 1];
                p1 += rv.z * dp1r[r4 * 4 + 2]; p2 += rv.z * dp2r[r4 * 4 + 2]; p3 += rv.z * dp3r[r4 * 4 + 2];
                p1 += rv.w * dp1r[r4 * 4 + 3]; p2 += rv.w * dp2r[r4 * 4 + 3]; p3 += rv.w * dp3r[r4 * 4 + 3];
            }
            const float w1 = p1 * c, w2 = p2 * c, w3 = p3 * c;
            const float vx = g.x, vy = g.y, vz = g.z;
            aI += w1;
            ax += w2 * vx; ay += w2 * vy; az += w2 * vz;
            const float t3x = w3 * vx, t3y = w3 * vy;
            mxx += t3x * vx; mxy += t3x * vy; mxz += t3x * vz;
            myy += t3y * vy; myz += t3y * vz; mzz += (w3 * vz) * vz;
        }

        // tensor_norm: || i0*I + skew(a) + (M - tr/3 I) ||_F^2
        const float tr3 = (mxx + myy + mzz) * (1.0f / 3.0f);
        const float t00 = aI + mxx - tr3;
        const float t11 = aI + myy - tr3;
        const float t22 = aI + mzz - tr3;
        const float tn = t00 * t00 + t11 * t11 + t22 * t22 +
                         2.0f * (mxy * mxy + az * az + mxz * mxz + ay * ay + myz * myz + ax * ax);

        // LayerNorm over 128 channels
        red[h] = tn;
        __syncthreads();
        for (int s = 64; s > 0; s >>= 1) { if (h < s) red[h] += red[h + s]; __syncthreads(); }
        const float mu = red[0] * (1.0f / 128.0f);
        __syncthreads();
        const float dv = tn - mu;
        red[h] = dv * dv;
        __syncthreads();
        for (int s = 64; s > 0; s >>= 1) { if (h < s) red[h] += red[h + s]; __syncthreads(); }
        const float var = red[0] * (1.0f / 128.0f);
        __syncthreads();   // red reused next node

        const int idx = n * 128 + h;
        nrm[idx] = dv * rsqrtf(var + 1e-5f) * gih + bih;
        acc[idx] = aI;
        acc[NH_TOT + idx] = ax;  acc[2 * NH_TOT + idx] = ay;  acc[3 * NH_TOT + idx] = az;
        acc[4 * NH_TOT + idx] = mxx; acc[5 * NH_TOT + idx] = mxy; acc[6 * NH_TOT + idx] = mxz;
        acc[7 * NH_TOT + idx] = myy; acc[8 * NH_TOT + idx] = myz; acc[9 * NH_TOT + idx] = mzz;
    }
}

// ---------------------------------------------------------------------------
// Generic fp32 GEMM: C(N x M) = act(A(N x K) @ B(M x K)^T + bias)
// 64x64 tile, 256 threads, 4x4 register blocking. act: 0 none, 1 silu
// ---------------------------------------------------------------------------
__device__ __forceinline__ void gemm_body(const float* __restrict__ A, const float* __restrict__ B,
                                          const float* __restrict__ bias, float* __restrict__ C,
                                          int K, int M, int act,
                                          float As[16][68], float Bs[16][68]) {
    const int tid = threadIdx.x;
    const int tx = tid & 15, ty = tid >> 4;
    const int n0 = blockIdx.x * 64, m0 = blockIdx.y * 64;
    const int lr = tid >> 2;
    const int lk = (tid & 3) * 4;
    float accv[4][4] = {};

    for (int kc = 0; kc < K; kc += 16) {
        const float4 a4 = *(const float4*)(A + (size_t)(n0 + lr) * K + kc + lk);
        const float4 b4 = *(const float4*)(B + (size_t)(m0 + lr) * K + kc + lk);
        __syncthreads();
        As[lk + 0][lr] = a4.x; As[lk + 1][lr] = a4.y; As[lk + 2][lr] = a4.z; As[lk + 3][lr] = a4.w;
        Bs[lk + 0][lr] = b4.x; Bs[lk + 1][lr] = b4.y; Bs[lk + 2][lr] = b4.z; Bs[lk + 3][lr] = b4.w;
        __syncthreads();
#pragma unroll
        for (int kk = 0; kk < 16; kk++) {
            const float4 av = *(const float4*)&As[kk][ty * 4];
            const float4 bv = *(const float4*)&Bs[kk][tx * 4];
            accv[0][0] += av.x * bv.x; accv[0][1] += av.x * bv.y; accv[0][2] += av.x * bv.z; accv[0][3] += av.x * bv.w;
            accv[1][0] += av.y * bv.x; accv[1][1] += av.y * bv.y; accv[1][2] += av.y * bv.z; accv[1][3] += av.y * bv.w;
            accv[2][0] += av.z * bv.x; accv[2][1] += av.z * bv.y; accv[2][2] += av.z * bv.z; accv[2][3] += av.z * bv.w;
            accv[3][0] += av.w * bv.x; accv[3][1] += av.w * bv.y; accv[3][2] += av.w * bv.z; accv[3][3] += av.w * bv.w;
        }
    }
#pragma unroll
    for (int i = 0; i < 4; i++) {
        float o[4];
#pragma unroll
        for (int j = 0; j < 4; j++) {
            float v = accv[i][j];
            if (bias) v += bias[m0 + tx * 4 + j];
            if (act) v = v / (1.0f + expf(-v));
            o[j] = v;
        }
        *(float4*)(C + (size_t)(n0 + ty * 4 + i) * M + m0 + tx * 4) = make_float4(o[0], o[1], o[2], o[3]);
    }
}

__global__ __launch_bounds__(256) void k_gemm(const float* __restrict__ A, const float* __restrict__ B,
                                              const float* __restrict__ bias, float* __restrict__ C,
                                              int K, int M, int act) {
    __shared__ float As[16][68], Bs[16][68];
    gemm_body(A, B, bias, C, K, M, act, As, Bs);
}

__global__ __launch_bounds__(256) void k_mix(const float* __restrict__ acc,
                                             const float* __restrict__ lt0,
                                             const float* __restrict__ lt1,
                                             const float* __restrict__ lt2,
                                             float* __restrict__ out10a,
                                             float* __restrict__ out10b) {
    __shared__ float As[16][68], Bs[16][68];
    const int c = blockIdx.z;
    const float* B = (c == 0) ? lt0 : ((c < 4) ? lt1 : lt2);
    float* C = (c < 5) ? (out10a + (size_t)c * NH_TOT) : (out10b + (size_t)(c - 5) * NH_TOT);
    gemm_body(acc + (size_t)c * NH_TOT, B, nullptr, C, 128, 128, 0, As, Bs);
}

// ---------------------------------------------------------------------------
// Fused combine (gates + Frobenius norms) + LayerNorm(384) -> x
// Block per node, 128 threads.
// ---------------------------------------------------------------------------
__global__ __launch_bounds__(128) void k_combine_ln(const float* __restrict__ out10a,
                                                    const float* __restrict__ out10b,
                                                    const float* __restrict__ scal,
                                                    const float* __restrict__ g,
                                                    const float* __restrict__ b,
                                                    float* __restrict__ x) {
    const int n = blockIdx.x, t = threadIdx.x;
    const int idx = n * 128 + t;
    __shared__ float red[128];
    const float i1  = out10a[idx];
    const float a1x = out10a[NH_TOT + idx], a1y = out10a[2 * NH_TOT + idx], a1z = out10a[3 * NH_TOT + idx];
    const float sxx = out10a[4 * NH_TOT + idx];
    const float sxy = out10b[idx], sxz = out10b[NH_TOT + idx];
    const float syy = out10b[2 * NH_TOT + idx], syz = out10b[3 * NH_TOT + idx], szz = out10b[4 * NH_TOT + idx];
    const float s0 = scal[n * 384 + 3 * t + 0];
    const float s1 = scal[n * 384 + 3 * t + 1];
    const float s2 = scal[n * 384 + 3 * t + 2];
    const float e0 = 3.0f * i1 * i1 * s0 * s0;
    const float e1 = 2.0f * (a1x * a1x + a1y * a1y + a1z * a1z) * s1 * s1;
    const float tr3 = (sxx + syy + szz) * (1.0f / 3.0f);
    const float d0s = sxx - tr3, d1s = syy - tr3, d2s = szz - tr3;
    const float e2 = (d0s * d0s + d1s * d1s + d2s * d2s +
                      2.0f * (sxy * sxy + sxz * sxz + syz * syz)) * s2 * s2;

    red[t] = e0 + e1 + e2;
    __syncthreads();
    for (int s = 64; s > 0; s >>= 1) { if (t < s) red[t] += red[t + s]; __syncthreads(); }
    const float mu = red[0] * (1.0f / 384.0f);
    __syncthreads();
    const float d0 = e0 - mu, d1 = e1 - mu, d2 = e2 - mu;
    red[t] = d0 * d0 + d1 * d1 + d2 * d2;
    __syncthreads();
    for (int s = 64; s > 0; s >>= 1) { if (t < s) red[t] += red[t + s]; __syncthreads(); }
    const float rs = rsqrtf(red[0] * (1.0f / 384.0f) + 1e-5f);
    x[n * 384 + t]       = d0 * rs * g[t]       + b[t];
    x[n * 384 + 128 + t] = d1 * rs * g[128 + t] + b[128 + t];
    x[n * 384 + 256 + t] = d2 * rs * g[256 + t] + b[256 + t];
}

// ---------------------------------------------------------------------------
// Fused MLP tail: s1 = silu(x@lin^T+b); s2 = silu(s1@ol1^T+b); out = s2@ol2^T+b
// 8 nodes per block, 128 threads.
// ---------------------------------------------------------------------------
__global__ __launch_bounds__(128) void k_tail(const float* __restrict__ x,
                                              const float* __restrict__ lin_w,
                                              const float* __restrict__ lin_b,
                                              const float* __restrict__ ol1_w,
                                              const float* __restrict__ ol1_b,
                                              const float* __restrict__ ol2_w,
                                              const float* __restrict__ ol2_b,
                                              float* __restrict__ out) {
    const int t = threadIdx.x;
    const int n0 = blockIdx.x * 8;
    __shared__ float sx[8 * 384];
    __shared__ float ss[8 * 128];

    const float4* xp = (const float4*)(x + (size_t)n0 * 384);
#pragma unroll
    for (int j = 0; j < 6; j++) ((float4*)sx)[t + j * 128] = xp[t + j * 128];
    __syncthreads();

    float a[8];
    const float lb = lin_b[t];
#pragma unroll
    for (int n = 0; n < 8; n++) a[n] = lb;
    const float4* wr = (const float4*)(lin_w + t * 384);
#pragma unroll 4
    for (int k4 = 0; k4 < 96; k4++) {
        const float4 w4 = wr[k4];
#pragma unroll
        for (int n = 0; n < 8; n++) {
            const float4 xv = *(const float4*)&sx[n * 384 + k4 * 4];
            a[n] += w4.x * xv.x + w4.y * xv.y + w4.z * xv.z + w4.w * xv.w;
        }
    }
#pragma unroll
    for (int n = 0; n < 8; n++) ss[n * 128 + t] = a[n] / (1.0f + expf(-a[n]));
    __syncthreads();

    const int o = t & 63, half = t >> 6;
    float accB[4];
    const float ob = ol1_b[o];
#pragma unroll
    for (int q = 0; q < 4; q++) accB[q] = ob;
    const float4* or4 = (const float4*)(ol1_w + o * 128);
#pragma unroll 4
    for (int k4 = 0; k4 < 32; k4++) {
        const float4 w4 = or4[k4];
#pragma unroll
        for (int q = 0; q < 4; q++) {
            const float4 sv = *(const float4*)&ss[(half + 2 * q) * 128 + k4 * 4];
            accB[q] += w4.x * sv.x + w4.y * sv.y + w4.z * sv.z + w4.w * sv.w;
        }
    }
    const float w2 = ol2_w[o];
#pragma unroll
    for (int q = 0; q < 4; q++) {
        float v = accB[q] / (1.0f + expf(-accB[q])) * w2;
        for (int s = 32; s > 0; s >>= 1) v += __shfl_down(v, s, 64);
        if (o == 0) out[n0 + half + 2 * q] = v + ol2_b[0];
    }
}

// ---------------------------------------------------------------------------
extern "C" void kernel_launch(void* const* d_in, const int* in_sizes, int n_in,
                              void* d_out, int out_size, void* d_ws, size_t ws_size,
                              hipStream_t stream) {
    (void)in_sizes; (void)n_in; (void)out_size; (void)ws_size;
    const float* edge_vec = (const float*)d_in[0];
    const float* emb_w   = (const float*)d_in[1];
    const float* emb2_w  = (const float*)d_in[2];
    const float* emb2_b  = (const float*)d_in[3];
    const float* dp1_w   = (const float*)d_in[4];
    const float* dp1_b   = (const float*)d_in[5];
    const float* dp2_w   = (const float*)d_in[6];
    const float* dp2_b   = (const float*)d_in[7];
    const float* dp3_w   = (const float*)d_in[8];
    const float* dp3_b   = (const float*)d_in[9];
    const float* lt0_w   = (const float*)d_in[10];
    const float* lt1_w   = (const float*)d_in[11];
    const float* lt2_w   = (const float*)d_in[12];
    const float* ls0_w   = (const float*)d_in[13];
    const float* ls0_b   = (const float*)d_in[14];
    const float* ls1_w   = (const float*)d_in[15];
    const float* ls1_b   = (const float*)d_in[16];
    const float* init_g  = (const float*)d_in[17];
    const float* init_b  = (const float*)d_in[18];
    const float* lin_w   = (const float*)d_in[19];
    const float* lin_b   = (const float*)d_in[20];
    const float* outn_g  = (const float*)d_in[21];
    const float* outn_b  = (const float*)d_in[22];
    const float* ol1_w   = (const float*)d_in[23];
    const float* ol1_b   = (const float*)d_in[24];
    const float* ol2_w   = (const float*)d_in[25];
    const float* ol2_b   = (const float*)d_in[26];
    const int* z  = (const int*)d_in[27];
    const int* ei = (const int*)d_in[28];
    float* out = (float*)d_out;

    char* w = (char*)d_ws;
    // --- setup region (dead after k_node) ---
    int*    cnt    = (int*)(w);                    // 16 KB
    int*    cursor = (int*)(w + 16384);            // 16 KB
    int*    off    = (int*)(w + 32768);            // 16.4 KB
    int*    order  = (int*)(w + 49408);            // 256 KB -> 311552
    float*  U1     = (float*)(w + 311552);         // 64 KB  -> 377088
    float*  U2     = (float*)(w + 377088);         // 64 KB  -> 442624
    int*    u2off  = (int*)(w + 442624);           // 256 KB -> 704768
    float4* geom   = (float4*)(w + 704768);        // 1 MB   -> 1753344
    float*  rbf_s  = (float*)(w + 1753344);        // 8 MB   -> 10141952
    // --- persistent region ---
    float* out10a = (float*)(w);                   // 10 MB, planes 0-4 (aliases dead setup)
    float* acc    = (float*)(w + 10485760);        // 20 MB -> 31457280
    float* nrm    = (float*)(w + 31457280);        // 2 MB  -> 33554432
    float* hbuf   = (float*)(w + 33554432);        // 4 MB  -> 37748736
    float* scal   = (float*)(w + 37748736);        // 6 MB  -> 44040192
    float* out10b = (float*)(w + 44040192);        // 10 MB, planes 5-9 -> 54525952
    float* xbuf   = acc;                           // acc dead after k_mix

    hipMemsetAsync(w, 0, 32768, stream);  // cnt + cursor
    k_u12<<<dim3(128), dim3(128), 0, stream>>>(emb_w, emb2_w, U1, U2);
    k_hist<<<dim3(256), dim3(256), 0, stream>>>(ei, cnt);
    k_scan<<<dim3(1), dim3(256), 0, stream>>>(cnt, off);
    k_scatter<<<dim3(256), dim3(256), 0, stream>>>(ei, off, cursor, order);
    k_edge<<<dim3(256), dim3(256), 0, stream>>>(edge_vec, ei, z, order, rbf_s, geom, u2off);
    k_node<<<dim3(2048), dim3(128), 0, stream>>>(z, off, rbf_s, geom, u2off, U1, U2, emb2_b,
                                                 dp1_w, dp1_b, dp2_w, dp2_b, dp3_w, dp3_b,
                                                 init_g, init_b, acc, nrm);
    k_gemm<<<dim3(64, 4), dim3(256), 0, stream>>>(nrm, ls0_w, ls0_b, hbuf, 128, 256, 1);
    k_gemm<<<dim3(64, 6), dim3(256), 0, stream>>>(hbuf, ls1_w, ls1_b, scal, 256, 384, 1);
    k_mix<<<dim3(64, 2, 10), dim3(256), 0, stream>>>(acc, lt0_w, lt1_w, lt2_w, out10a, out10b);
    k_combine_ln<<<dim3(4096), dim3(128), 0, stream>>>(out10a, out10b, scal, outn_g, outn_b, xbuf);
    k_tail<<<dim3(512), dim3(128), 0, stream>>>(xbuf, lin_w, lin_b, ol1_w, ol1_b, ol2_w, ol2_b, out);
}

// Round 3
// 276.150 us; speedup vs baseline: 1.0806x; 1.0722x over previous
//
#include <hip/hip_runtime.h>
#include <math.h>

#define NH_TOT 524288   // 4096*128
#define N_ATOM 4096
#define N_EDGE 65536

typedef __attribute__((ext_vector_type(8))) short bf16x8;
typedef __attribute__((ext_vector_type(4))) float f32x4;

__device__ __forceinline__ unsigned short f2bf(float f) {
    unsigned u = __builtin_bit_cast(unsigned, f);
    unsigned r = (u + 0x7fffu + ((u >> 16) & 1u)) >> 16;
    return (unsigned short)r;
}

// ---------------------------------------------------------------------------
// Fused setup: blocks [0,64): U1/U2 tables; [64,320): edge precompute + hist;
// [320,496): weight fp32->bf16 conversion into wb.
// wb layout (elements): ls0@0, ls1@32768, lt0@131072, lt1@147456, lt2@163840
// ---------------------------------------------------------------------------
__global__ __launch_bounds__(256) void k_setup(
    const float* __restrict__ emb_w, const float* __restrict__ emb2_w,
    const float* __restrict__ edge_vec, const int* __restrict__ ei,
    const int* __restrict__ z,
    const float* __restrict__ ls0_w, const float* __restrict__ ls1_w,
    const float* __restrict__ lt0_w, const float* __restrict__ lt1_w,
    const float* __restrict__ lt2_w,
    float* __restrict__ U1, float* __restrict__ U2,
    int* __restrict__ cnt, int* __restrict__ u2off,
    float4* __restrict__ geom, float* __restrict__ rbf_s,
    unsigned short* __restrict__ wb) {
    const int bx = blockIdx.x, tid = threadIdx.x;
    if (bx < 64) {
        // U tables: 2 z-types per block
        __shared__ float se[2][128];
        const int t = bx * 2 + (tid >> 7), h = tid & 127, half = tid >> 7;
        se[half][h] = emb_w[t * 128 + h];
        __syncthreads();
        float u1 = 0.f, u2 = 0.f;
        const float* row = emb2_w + h * 256;
#pragma unroll 8
        for (int k = 0; k < 128; k++) {
            u1 += se[half][k] * row[k];
            u2 += se[half][k] * row[128 + k];
        }
        U1[t * 128 + h] = u1;
        U2[t * 128 + h] = u2;
    } else if (bx < 320) {
        const int e = (bx - 64) * 256 + tid;
        const int src = ei[e];
        atomicAdd(&cnt[src], 1);
        u2off[e] = z[ei[N_EDGE + e]] << 7;
        const float evx = edge_vec[3 * e + 0];
        const float evy = edge_vec[3 * e + 1];
        const float evz = edge_vec[3 * e + 2];
        const float d = sqrtf(evx * evx + evy * evy + evz * evz);
        const float inv = 1.0f / d;
        const float cut = (d < 4.5f) ? 0.5f * (cosf(0.6981317007977318f * d) + 1.0f) : 0.0f;
        geom[e] = make_float4(evx * inv, evy * inv, evz * inv, cut);
        const float expd = expf(-1.1111111111111112f * d);
        const float m0 = 0.011108996538242306f;
        const float dm = (1.0f - m0) * (1.0f / 31.0f);
        const float tb = 0.0625f * (1.0f - m0);
        const float beta = 1.0f / (tb * tb);
        float rv[32];
#pragma unroll
        for (int r = 0; r < 32; r++) {
            const float df = expd - (m0 + (float)r * dm);
            rv[r] = cut * expf(-beta * df * df);
        }
        float4* dst = (float4*)(rbf_s + (size_t)e * 32);
#pragma unroll
        for (int j = 0; j < 8; j++) dst[j] = ((const float4*)rv)[j];
    } else {
        // weight conversion; each 1024-elem block chunk lies in one source
        const int base = (bx - 320) * 1024 + tid * 4;
        const float* src;
        int off;
        if (base < 32768)       { src = ls0_w; off = 0; }
        else if (base < 131072) { src = ls1_w; off = 32768; }
        else if (base < 147456) { src = lt0_w; off = 131072; }
        else if (base < 163840) { src = lt1_w; off = 147456; }
        else                    { src = lt2_w; off = 163840; }
        const float4 v = *(const float4*)(src + (base - off));
        unsigned short* o = wb + base;
        o[0] = f2bf(v.x); o[1] = f2bf(v.y); o[2] = f2bf(v.z); o[3] = f2bf(v.w);
    }
}

// ---------------------------------------------------------------------------
// CSR: scan + scatter
// ---------------------------------------------------------------------------
__global__ __launch_bounds__(256) void k_scan(const int* __restrict__ cnt, int* __restrict__ off) {
    __shared__ int s[256];
    const int t = threadIdx.x;
    int loc[16];
    int run = 0;
#pragma unroll
    for (int i = 0; i < 16; i++) { run += cnt[t * 16 + i]; loc[i] = run; }
    s[t] = run;
    __syncthreads();
    for (int d = 1; d < 256; d <<= 1) {
        const int add = (t >= d) ? s[t - d] : 0;
        __syncthreads();
        s[t] += add;
        __syncthreads();
    }
    const int base = s[t] - run;
    if (t == 0) off[0] = 0;
#pragma unroll
    for (int i = 0; i < 16; i++) off[t * 16 + i + 1] = base + loc[i];
}

__global__ __launch_bounds__(256) void k_scatter(const int* __restrict__ ei,
                                                 const int* __restrict__ off,
                                                 int* __restrict__ cursor,
                                                 int* __restrict__ order) {
    const int e = blockIdx.x * 256 + threadIdx.x;
    const int s = ei[e];
    const int pos = off[s] + atomicAdd(&cursor[s], 1);
    order[pos] = e;
}

// ---------------------------------------------------------------------------
// Per-node accumulation + tensor_norm + LayerNorm(init). 1 node/block,
// 128 threads = channels. launch_bounds(128,2) keeps dp weights in VGPRs.
// Outputs bf16 acc planes + bf16 nrm.
// ---------------------------------------------------------------------------
__global__ __launch_bounds__(128, 2) void k_node(
    const int* __restrict__ z, const int* __restrict__ off,
    const int* __restrict__ order,
    const float* __restrict__ rbf_s, const float4* __restrict__ geom,
    const int* __restrict__ u2off,
    const float* __restrict__ U1, const float* __restrict__ U2,
    const float* __restrict__ emb2_b,
    const float* __restrict__ dp1_w, const float* __restrict__ dp1_b,
    const float* __restrict__ dp2_w, const float* __restrict__ dp2_b,
    const float* __restrict__ dp3_w, const float* __restrict__ dp3_b,
    const float* __restrict__ init_g, const float* __restrict__ init_b,
    unsigned short* __restrict__ acc_bf, unsigned short* __restrict__ nrm_bf) {
    const int n = blockIdx.x, h = threadIdx.x;
    const int beg = off[n], end = off[n + 1];

    float dp1r[32], dp2r[32], dp3r[32];
    {
        const float4* p1 = (const float4*)(dp1_w + h * 32);
        const float4* p2 = (const float4*)(dp2_w + h * 32);
        const float4* p3 = (const float4*)(dp3_w + h * 32);
#pragma unroll
        for (int j = 0; j < 8; j++) {
            ((float4*)dp1r)[j] = p1[j];
            ((float4*)dp2r)[j] = p2[j];
            ((float4*)dp3r)[j] = p3[j];
        }
    }
    const float u1h = U1[(z[n] << 7) + h];
    const float bh = emb2_b[h];
    const float b1 = dp1_b[h], b2 = dp2_b[h], b3 = dp3_b[h];

    float aI = 0.f, ax = 0.f, ay = 0.f, az = 0.f;
    float mxx = 0.f, mxy = 0.f, mxz = 0.f, myy = 0.f, myz = 0.f, mzz = 0.f;

    __shared__ float red[128];

#pragma unroll 2
    for (int i = beg; i < end; i++) {
        const int e = order[i];
        const float4 g = geom[e];
        const float u2v = U2[u2off[e] + h];
        const float c = g.w * (u1h + u2v + bh);
        float p1 = b1, p2 = b2, p3 = b3;
        const float4* rp = (const float4*)(rbf_s + (size_t)e * 32);
#pragma unroll
        for (int r4 = 0; r4 < 8; r4++) {
            const float4 rv = rp[r4];
            p1 += rv.x * dp1r[r4 * 4 + 0]; p2 += rv.x * dp2r[r4 * 4 + 0]; p3 += rv.x * dp3r[r4 * 4 + 0];
            p1 += rv.y * dp1r[r4 * 4 + 1]; p2 += rv.y * dp2r[r4 * 4 + 1]; p3 += rv.y * dp3r[r4 * 4 + 1];
            p1 += rv.z * dp1r[r4 * 4 + 2]; p2 += rv.z * dp2r[r4 * 4 + 2]; p3 += rv.z * dp3r[r4 * 4 + 2];
            p1 += rv.w * dp1r[r4 * 4 + 3]; p2 += rv.w * dp2r[r4 * 4 + 3]; p3 += rv.w * dp3r[r4 * 4 + 3];
        }
        const float w1 = p1 * c, w2 = p2 * c, w3 = p3 * c;
        const float vx = g.x, vy = g.y, vz = g.z;
        aI += w1;
        ax += w2 * vx; ay += w2 * vy; az += w2 * vz;
        const float t3x = w3 * vx, t3y = w3 * vy;
        mxx += t3x * vx; mxy += t3x * vy; mxz += t3x * vz;
        myy += t3y * vy; myz += t3y * vz; mzz += (w3 * vz) * vz;
    }

    const float tr3 = (mxx + myy + mzz) * (1.0f / 3.0f);
    const float t00 = aI + mxx - tr3;
    const float t11 = aI + myy - tr3;
    const float t22 = aI + mzz - tr3;
    const float tn = t00 * t00 + t11 * t11 + t22 * t22 +
                     2.0f * (mxy * mxy + az * az + mxz * mxz + ay * ay + myz * myz + ax * ax);

    red[h] = tn;
    __syncthreads();
    for (int s = 64; s > 0; s >>= 1) { if (h < s) red[h] += red[h + s]; __syncthreads(); }
    const float mu = red[0] * (1.0f / 128.0f);
    __syncthreads();
    const float dv = tn - mu;
    red[h] = dv * dv;
    __syncthreads();
    for (int s = 64; s > 0; s >>= 1) { if (h < s) red[h] += red[h + s]; __syncthreads(); }
    const float var = red[0] * (1.0f / 128.0f);

    const int idx = n * 128 + h;
    nrm_bf[idx] = f2bf(dv * rsqrtf(var + 1e-5f) * init_g[h] + init_b[h]);
    acc_bf[idx] = f2bf(aI);
    acc_bf[NH_TOT + idx] = f2bf(ax);  acc_bf[2 * NH_TOT + idx] = f2bf(ay);  acc_bf[3 * NH_TOT + idx] = f2bf(az);
    acc_bf[4 * NH_TOT + idx] = f2bf(mxx); acc_bf[5 * NH_TOT + idx] = f2bf(mxy); acc_bf[6 * NH_TOT + idx] = f2bf(mxz);
    acc_bf[7 * NH_TOT + idx] = f2bf(myy); acc_bf[8 * NH_TOT + idx] = f2bf(myz); acc_bf[9 * NH_TOT + idx] = f2bf(mzz);
}

// ---------------------------------------------------------------------------
// Fused gate MLP: scal = silu(ls1 @ silu(ls0 @ nrm + b0) + b1), MFMA bf16.
// Block = 64 nodes, 256 threads (4 waves). GEMM1: 64x256 K=128; GEMM2: 64x384 K=256.
// ---------------------------------------------------------------------------
__global__ __launch_bounds__(256) void k_gates(const unsigned short* __restrict__ nrm_bf,
                                               const unsigned short* __restrict__ wb,
                                               const float* __restrict__ ls0_b,
                                               const float* __restrict__ ls1_b,
                                               float* __restrict__ scal) {
    __shared__ unsigned short h1[64][272];   // 64x256 bf16, stride 272 (16B aligned)
    const int tid = threadIdx.x;
    const int wave = tid >> 6, lane = tid & 63;
    const int lm = lane & 15, lq = lane >> 4;
    const int m0 = blockIdx.x * 64;

    {
        f32x4 acc[4][4];
#pragma unroll
        for (int i = 0; i < 4; i++)
#pragma unroll
            for (int j = 0; j < 4; j++) acc[i][j] = (f32x4){0.f, 0.f, 0.f, 0.f};
        const int n0 = wave * 64;
#pragma unroll
        for (int kc = 0; kc < 128; kc += 32) {
            bf16x8 af[4], bfr[4];
#pragma unroll
            for (int sm = 0; sm < 4; sm++)
                af[sm] = *(const bf16x8*)(nrm_bf + (size_t)(m0 + sm * 16 + lm) * 128 + kc + lq * 8);
#pragma unroll
            for (int sn = 0; sn < 4; sn++)
                bfr[sn] = *(const bf16x8*)(wb + (size_t)(n0 + sn * 16 + lm) * 128 + kc + lq * 8);
#pragma unroll
            for (int sm = 0; sm < 4; sm++)
#pragma unroll
                for (int sn = 0; sn < 4; sn++)
                    acc[sm][sn] = __builtin_amdgcn_mfma_f32_16x16x32_bf16(af[sm], bfr[sn], acc[sm][sn], 0, 0, 0);
        }
#pragma unroll
        for (int sm = 0; sm < 4; sm++)
#pragma unroll
            for (int sn = 0; sn < 4; sn++) {
                const int col = n0 + sn * 16 + lm;
                const float bv = ls0_b[col];
                const int r0 = sm * 16 + lq * 4;
#pragma unroll
                for (int r = 0; r < 4; r++) {
                    float v = acc[sm][sn][r] + bv;
                    v = v / (1.0f + expf(-v));
                    h1[r0 + r][col] = f2bf(v);
                }
            }
    }
    __syncthreads();
    {
        f32x4 acc[4][6];
#pragma unroll
        for (int i = 0; i < 4; i++)
#pragma unroll
            for (int j = 0; j < 6; j++) acc[i][j] = (f32x4){0.f, 0.f, 0.f, 0.f};
        const int n0 = wave * 96;
        const unsigned short* ls1p = wb + 32768;
#pragma unroll 2
        for (int kc = 0; kc < 256; kc += 32) {
            bf16x8 af[4], bfr[6];
#pragma unroll
            for (int sm = 0; sm < 4; sm++)
                af[sm] = *(const bf16x8*)(&h1[sm * 16 + lm][kc + lq * 8]);
#pragma unroll
            for (int sn = 0; sn < 6; sn++)
                bfr[sn] = *(const bf16x8*)(ls1p + (size_t)(n0 + sn * 16 + lm) * 256 + kc + lq * 8);
#pragma unroll
            for (int sm = 0; sm < 4; sm++)
#pragma unroll
                for (int sn = 0; sn < 6; sn++)
                    acc[sm][sn] = __builtin_amdgcn_mfma_f32_16x16x32_bf16(af[sm], bfr[sn], acc[sm][sn], 0, 0, 0);
        }
#pragma unroll
        for (int sm = 0; sm < 4; sm++)
#pragma unroll
            for (int sn = 0; sn < 6; sn++) {
                const int col = n0 + sn * 16 + lm;
                const float bv = ls1_b[col];
                const int r0 = sm * 16 + lq * 4;
#pragma unroll
                for (int r = 0; r < 4; r++) {
                    float v = acc[sm][sn][r] + bv;
                    v = v / (1.0f + expf(-v));
                    scal[(size_t)(m0 + r0 + r) * 384 + col] = v;
                }
            }
    }
}

// ---------------------------------------------------------------------------
// Mix: out10[p] = acc[p] @ lt(p)^T, MFMA bf16, fp32 out. Block tile 128x128.
// ---------------------------------------------------------------------------
__global__ __launch_bounds__(256) void k_mix(const unsigned short* __restrict__ acc_bf,
                                             const unsigned short* __restrict__ wb,
                                             float* __restrict__ out10) {
    const int p = blockIdx.y;
    const unsigned short* A = acc_bf + (size_t)p * NH_TOT;
    const unsigned short* B = wb + (p == 0 ? 131072 : (p < 4 ? 147456 : 163840));
    float* C = out10 + (size_t)p * NH_TOT;
    const int tid = threadIdx.x, wave = tid >> 6, lane = tid & 63;
    const int lm = lane & 15, lq = lane >> 4;
    const int m0 = blockIdx.x * 128 + (wave >> 1) * 64;
    const int n0 = (wave & 1) * 64;

    f32x4 acc[4][4];
#pragma unroll
    for (int i = 0; i < 4; i++)
#pragma unroll
        for (int j = 0; j < 4; j++) acc[i][j] = (f32x4){0.f, 0.f, 0.f, 0.f};
#pragma unroll
    for (int kc = 0; kc < 128; kc += 32) {
        bf16x8 af[4], bfr[4];
#pragma unroll
        for (int sm = 0; sm < 4; sm++)
            af[sm] = *(const bf16x8*)(A + (size_t)(m0 + sm * 16 + lm) * 128 + kc + lq * 8);
#pragma unroll
        for (int sn = 0; sn < 4; sn++)
            bfr[sn] = *(const bf16x8*)(B + (size_t)(n0 + sn * 16 + lm) * 128 + kc + lq * 8);
#pragma unroll
        for (int sm = 0; sm < 4; sm++)
#pragma unroll
            for (int sn = 0; sn < 4; sn++)
                acc[sm][sn] = __builtin_amdgcn_mfma_f32_16x16x32_bf16(af[sm], bfr[sn], acc[sm][sn], 0, 0, 0);
    }
#pragma unroll
    for (int sm = 0; sm < 4; sm++)
#pragma unroll
        for (int sn = 0; sn < 4; sn++) {
            const int col = n0 + sn * 16 + lm;
            const int r0 = sm * 16 + lq * 4;
#pragma unroll
            for (int r = 0; r < 4; r++)
                C[(size_t)(m0 + r0 + r) * 128 + col] = acc[sm][sn][r];
        }
}

// ---------------------------------------------------------------------------
// Fused combine + LN(384) + MLP tail. 8 nodes/block, 128 threads.
// ---------------------------------------------------------------------------
__global__ __launch_bounds__(128) void k_comb_tail(
    const float* __restrict__ out10, const float* __restrict__ scal,
    const float* __restrict__ g, const float* __restrict__ b,
    const float* __restrict__ lin_w, const float* __restrict__ lin_b,
    const float* __restrict__ ol1_w, const float* __restrict__ ol1_b,
    const float* __restrict__ ol2_w, const float* __restrict__ ol2_b,
    float* __restrict__ out) {
    const int tid = threadIdx.x;
    const int n0 = blockIdx.x * 8;
    const int wave = tid >> 6;
    __shared__ float sx[8 * 384];
    __shared__ float ss[8 * 128];
    __shared__ float cross[2][2];

    const float g0 = g[tid], g1 = g[128 + tid], g2 = g[256 + tid];
    const float bb0 = b[tid], bb1 = b[128 + tid], bb2 = b[256 + tid];

    for (int nn = 0; nn < 8; nn++) {
        const int n = n0 + nn;
        const size_t idx = (size_t)n * 128 + tid;
        const float i1  = out10[idx];
        const float a1x = out10[NH_TOT + idx], a1y = out10[2 * NH_TOT + idx], a1z = out10[3 * NH_TOT + idx];
        const float sxx = out10[4 * NH_TOT + idx], sxy = out10[5 * NH_TOT + idx], sxz = out10[6 * NH_TOT + idx];
        const float syy = out10[7 * NH_TOT + idx], syz = out10[8 * NH_TOT + idx], szz = out10[9 * NH_TOT + idx];
        const float s0 = scal[(size_t)n * 384 + 3 * tid + 0];
        const float s1 = scal[(size_t)n * 384 + 3 * tid + 1];
        const float s2 = scal[(size_t)n * 384 + 3 * tid + 2];
        const float e0 = 3.0f * i1 * i1 * s0 * s0;
        const float e1 = 2.0f * (a1x * a1x + a1y * a1y + a1z * a1z) * s1 * s1;
        const float tr3 = (sxx + syy + szz) * (1.0f / 3.0f);
        const float d0s = sxx - tr3, d1s = syy - tr3, d2s = szz - tr3;
        const float e2 = (d0s * d0s + d1s * d1s + d2s * d2s +
                          2.0f * (sxy * sxy + sxz * sxz + syz * syz)) * s2 * s2;

        float S = e0 + e1 + e2;
        for (int o = 32; o > 0; o >>= 1) S += __shfl_down(S, o, 64);
        if ((tid & 63) == 0) cross[wave][0] = S;
        __syncthreads();
        const float mu = (cross[0][0] + cross[1][0]) * (1.0f / 384.0f);
        const float d0 = e0 - mu, d1 = e1 - mu, d2 = e2 - mu;
        float Q = d0 * d0 + d1 * d1 + d2 * d2;
        for (int o = 32; o > 0; o >>= 1) Q += __shfl_down(Q, o, 64);
        __syncthreads();
        if ((tid & 63) == 0) cross[wave][1] = Q;
        __syncthreads();
        const float var = (cross[0][1] + cross[1][1]) * (1.0f / 384.0f);
        const float rs = rsqrtf(var + 1e-5f);
        sx[nn * 384 + tid]       = d0 * rs * g0 + bb0;
        sx[nn * 384 + 128 + tid] = d1 * rs * g1 + bb1;
        sx[nn * 384 + 256 + tid] = d2 * rs * g2 + bb2;
        __syncthreads();
    }

    // lin: s1 = silu(x @ lin^T + b)
    float a[8];
    const float lb = lin_b[tid];
#pragma unroll
    for (int n = 0; n < 8; n++) a[n] = lb;
    const float4* wr = (const float4*)(lin_w + tid * 384);
#pragma unroll 4
    for (int k4 = 0; k4 < 96; k4++) {
        const float4 w4 = wr[k4];
#pragma unroll
        for (int n = 0; n < 8; n++) {
            const float4 xv = *(const float4*)&sx[n * 384 + k4 * 4];
            a[n] += w4.x * xv.x + w4.y * xv.y + w4.z * xv.z + w4.w * xv.w;
        }
    }
#pragma unroll
    for (int n = 0; n < 8; n++) ss[n * 128 + tid] = a[n] / (1.0f + expf(-a[n]));
    __syncthreads();

    const int o = tid & 63, half = tid >> 6;
    float accB[4];
    const float ob = ol1_b[o];
#pragma unroll
    for (int q = 0; q < 4; q++) accB[q] = ob;
    const float4* or4 = (const float4*)(ol1_w + o * 128);
#pragma unroll 4
    for (int k4 = 0; k4 < 32; k4++) {
        const float4 w4 = or4[k4];
#pragma unroll
        for (int q = 0; q < 4; q++) {
            const float4 sv = *(const float4*)&ss[(half + 2 * q) * 128 + k4 * 4];
            accB[q] += w4.x * sv.x + w4.y * sv.y + w4.z * sv.z + w4.w * sv.w;
        }
    }
    const float w2 = ol2_w[o];
#pragma unroll
    for (int q = 0; q < 4; q++) {
        float v = accB[q] / (1.0f + expf(-accB[q])) * w2;
        for (int s = 32; s > 0; s >>= 1) v += __shfl_down(v, s, 64);
        if (o == 0) out[n0 + half + 2 * q] = v + ol2_b[0];
    }
}

// ---------------------------------------------------------------------------
extern "C" void kernel_launch(void* const* d_in, const int* in_sizes, int n_in,
                              void* d_out, int out_size, void* d_ws, size_t ws_size,
                              hipStream_t stream) {
    (void)in_sizes; (void)n_in; (void)out_size; (void)ws_size;
    const float* edge_vec = (const float*)d_in[0];
    const float* emb_w   = (const float*)d_in[1];
    const float* emb2_w  = (const float*)d_in[2];
    const float* emb2_b  = (const float*)d_in[3];
    const float* dp1_w   = (const float*)d_in[4];
    const float* dp1_b   = (const float*)d_in[5];
    const float* dp2_w   = (const float*)d_in[6];
    const float* dp2_b   = (const float*)d_in[7];
    const float* dp3_w   = (const float*)d_in[8];
    const float* dp3_b   = (const float*)d_in[9];
    const float* lt0_w   = (const float*)d_in[10];
    const float* lt1_w   = (const float*)d_in[11];
    const float* lt2_w   = (const float*)d_in[12];
    const float* ls0_w   = (const float*)d_in[13];
    const float* ls0_b   = (const float*)d_in[14];
    const float* ls1_w   = (const float*)d_in[15];
    const float* ls1_b   = (const float*)d_in[16];
    const float* init_g  = (const float*)d_in[17];
    const float* init_b  = (const float*)d_in[18];
    const float* lin_w   = (const float*)d_in[19];
    const float* lin_b   = (const float*)d_in[20];
    const float* outn_g  = (const float*)d_in[21];
    const float* outn_b  = (const float*)d_in[22];
    const float* ol1_w   = (const float*)d_in[23];
    const float* ol1_b   = (const float*)d_in[24];
    const float* ol2_w   = (const float*)d_in[25];
    const float* ol2_b   = (const float*)d_in[26];
    const int* z  = (const int*)d_in[27];
    const int* ei = (const int*)d_in[28];
    float* out = (float*)d_out;

    char* w = (char*)d_ws;
    int*            cnt    = (int*)(w);                       // 16 KB
    int*            cursor = (int*)(w + 16384);               // 16 KB
    int*            off    = (int*)(w + 32768);               // -> 49408 (padded)
    int*            order  = (int*)(w + 49408);               // -> 311552
    float*          U1     = (float*)(w + 311552);            // -> 377088
    float*          U2     = (float*)(w + 377088);            // -> 442624
    int*            u2off  = (int*)(w + 442624);              // -> 704768
    float4*         geom   = (float4*)(w + 704768);           // -> 1753344
    float*          rbf_s  = (float*)(w + 1753344);           // -> 10141952
    unsigned short* wb     = (unsigned short*)(w + 10141952); // -> 10502400
    unsigned short* nrm_bf = (unsigned short*)(w + 10502400); // -> 11550976
    unsigned short* acc_bf = (unsigned short*)(w + 11550976); // -> 22036736
    float*          scal   = (float*)(w + 22036736);          // -> 28328192
    float*          out10  = (float*)(w + 28328192);          // -> 49299712

    hipMemsetAsync(w, 0, 32768, stream);  // cnt + cursor
    k_setup<<<dim3(496), dim3(256), 0, stream>>>(emb_w, emb2_w, edge_vec, ei, z,
                                                 ls0_w, ls1_w, lt0_w, lt1_w, lt2_w,
                                                 U1, U2, cnt, u2off, geom, rbf_s, wb);
    k_scan<<<dim3(1), dim3(256), 0, stream>>>(cnt, off);
    k_scatter<<<dim3(256), dim3(256), 0, stream>>>(ei, off, cursor, order);
    k_node<<<dim3(4096), dim3(128), 0, stream>>>(z, off, order, rbf_s, geom, u2off, U1, U2,
                                                 emb2_b, dp1_w, dp1_b, dp2_w, dp2_b, dp3_w, dp3_b,
                                                 init_g, init_b, acc_bf, nrm_bf);
    k_gates<<<dim3(64), dim3(256), 0, stream>>>(nrm_bf, wb, ls0_b, ls1_b, scal);
    k_mix<<<dim3(32, 10), dim3(256), 0, stream>>>(acc_bf, wb, out10);
    k_comb_tail<<<dim3(512), dim3(128), 0, stream>>>(out10, scal, outn_g, outn_b,
                                                     lin_w, lin_b, ol1_w, ol1_b, ol2_w, ol2_b, out);
}

// Round 4
// 265.010 us; speedup vs baseline: 1.1260x; 1.0420x over previous
//
#include <hip/hip_runtime.h>
#include <math.h>

#define NH_TOT 524288   // 4096*128
#define N_ATOM 4096
#define N_EDGE 65536

typedef __attribute__((ext_vector_type(8))) short bf16x8;
typedef __attribute__((ext_vector_type(4))) float f32x4;

__device__ __forceinline__ unsigned short f2bf(float f) {
    unsigned u = __builtin_bit_cast(unsigned, f);
    unsigned r = (u + 0x7fffu + ((u >> 16) & 1u)) >> 16;
    return (unsigned short)r;
}
__device__ __forceinline__ float silu(float v) { return v / (1.0f + expf(-v)); }

// ---------------------------------------------------------------------------
// Fused setup: blocks [0,64): U1/U2 tables; [64,320): edge precompute + hist;
// [320,496): weight fp32->bf16 conversion into wb.
// wb layout (elements): ls0@0, ls1@32768, lt0@131072, lt1@147456, lt2@163840
// ---------------------------------------------------------------------------
__global__ __launch_bounds__(256) void k_setup(
    const float* __restrict__ emb_w, const float* __restrict__ emb2_w,
    const float* __restrict__ edge_vec, const int* __restrict__ ei,
    const int* __restrict__ z,
    const float* __restrict__ ls0_w, const float* __restrict__ ls1_w,
    const float* __restrict__ lt0_w, const float* __restrict__ lt1_w,
    const float* __restrict__ lt2_w,
    float* __restrict__ U1, float* __restrict__ U2,
    int* __restrict__ cnt, int* __restrict__ u2off,
    float4* __restrict__ geom, float* __restrict__ rbf_s,
    unsigned short* __restrict__ wb) {
    const int bx = blockIdx.x, tid = threadIdx.x;
    if (bx < 64) {
        __shared__ float se[2][128];
        const int t = bx * 2 + (tid >> 7), h = tid & 127, half = tid >> 7;
        se[half][h] = emb_w[t * 128 + h];
        __syncthreads();
        float u1 = 0.f, u2 = 0.f;
        const float* row = emb2_w + h * 256;
#pragma unroll 8
        for (int k = 0; k < 128; k++) {
            u1 += se[half][k] * row[k];
            u2 += se[half][k] * row[128 + k];
        }
        U1[t * 128 + h] = u1;
        U2[t * 128 + h] = u2;
    } else if (bx < 320) {
        const int e = (bx - 64) * 256 + tid;
        const int src = ei[e];
        atomicAdd(&cnt[src], 1);
        u2off[e] = z[ei[N_EDGE + e]] << 7;
        const float evx = edge_vec[3 * e + 0];
        const float evy = edge_vec[3 * e + 1];
        const float evz = edge_vec[3 * e + 2];
        const float d = sqrtf(evx * evx + evy * evy + evz * evz);
        const float inv = 1.0f / d;
        const float cut = (d < 4.5f) ? 0.5f * (cosf(0.6981317007977318f * d) + 1.0f) : 0.0f;
        geom[e] = make_float4(evx * inv, evy * inv, evz * inv, cut);
        const float expd = expf(-1.1111111111111112f * d);
        const float m0 = 0.011108996538242306f;
        const float dm = (1.0f - m0) * (1.0f / 31.0f);
        const float tb = 0.0625f * (1.0f - m0);
        const float beta = 1.0f / (tb * tb);
        float rv[32];
#pragma unroll
        for (int r = 0; r < 32; r++) {
            const float df = expd - (m0 + (float)r * dm);
            rv[r] = cut * expf(-beta * df * df);
        }
        float4* dst = (float4*)(rbf_s + (size_t)e * 32);
#pragma unroll
        for (int j = 0; j < 8; j++) dst[j] = ((const float4*)rv)[j];
    } else {
        const int base = (bx - 320) * 1024 + tid * 4;
        const float* src;
        int off;
        if (base < 32768)       { src = ls0_w; off = 0; }
        else if (base < 131072) { src = ls1_w; off = 32768; }
        else if (base < 147456) { src = lt0_w; off = 131072; }
        else if (base < 163840) { src = lt1_w; off = 147456; }
        else                    { src = lt2_w; off = 163840; }
        const float4 v = *(const float4*)(src + (base - off));
        unsigned short* o = wb + base;
        o[0] = f2bf(v.x); o[1] = f2bf(v.y); o[2] = f2bf(v.z); o[3] = f2bf(v.w);
    }
}

// ---------------------------------------------------------------------------
// CSR: scan + scatter
// ---------------------------------------------------------------------------
__global__ __launch_bounds__(256) void k_scan(const int* __restrict__ cnt, int* __restrict__ off) {
    __shared__ int s[256];
    const int t = threadIdx.x;
    int loc[16];
    int run = 0;
#pragma unroll
    for (int i = 0; i < 16; i++) { run += cnt[t * 16 + i]; loc[i] = run; }
    s[t] = run;
    __syncthreads();
    for (int d = 1; d < 256; d <<= 1) {
        const int add = (t >= d) ? s[t - d] : 0;
        __syncthreads();
        s[t] += add;
        __syncthreads();
    }
    const int base = s[t] - run;
    if (t == 0) off[0] = 0;
#pragma unroll
    for (int i = 0; i < 16; i++) off[t * 16 + i + 1] = base + loc[i];
}

__global__ __launch_bounds__(256) void k_scatter(const int* __restrict__ ei,
                                                 const int* __restrict__ off,
                                                 int* __restrict__ cursor,
                                                 int* __restrict__ order) {
    const int e = blockIdx.x * 256 + threadIdx.x;
    const int s = ei[e];
    const int pos = off[s] + atomicAdd(&cursor[s], 1);
    order[pos] = e;
}

// ---------------------------------------------------------------------------
// Per-node accumulation, 3 channel-groups (384 threads):
//   grp0 (tid 0-127):   w1 path -> plane 0 (aI)
//   grp1 (tid 128-255): w2 path -> planes 1-3 (ax,ay,az)
//   grp2 (tid 256-383): w3 path -> planes 4-9 (Mxx..Mzz)
// Each thread holds only 32 weight floats (8 float4) => register-resident.
// Cross-group LDS combine for tensor_norm + LayerNorm(init).
// ---------------------------------------------------------------------------
__global__ __launch_bounds__(384, 1) void k_node(
    const int* __restrict__ z, const int* __restrict__ off,
    const int* __restrict__ order,
    const float* __restrict__ rbf_s, const float4* __restrict__ geom,
    const int* __restrict__ u2off,
    const float* __restrict__ U1, const float* __restrict__ U2,
    const float* __restrict__ emb2_b,
    const float* __restrict__ dp1_w, const float* __restrict__ dp1_b,
    const float* __restrict__ dp2_w, const float* __restrict__ dp2_b,
    const float* __restrict__ dp3_w, const float* __restrict__ dp3_b,
    const float* __restrict__ init_g, const float* __restrict__ init_b,
    unsigned short* __restrict__ acc_bf, unsigned short* __restrict__ nrm_bf) {
    const int n = blockIdx.x, tid = threadIdx.x;
    const int h = tid & 127, grp = tid >> 7;
    const int beg = off[n], end = off[n + 1];

    const float* dpw = (grp == 0 ? dp1_w : (grp == 1 ? dp2_w : dp3_w)) + h * 32;
    const float4 w0 = ((const float4*)dpw)[0];
    const float4 w1 = ((const float4*)dpw)[1];
    const float4 w2 = ((const float4*)dpw)[2];
    const float4 w3 = ((const float4*)dpw)[3];
    const float4 w4 = ((const float4*)dpw)[4];
    const float4 w5 = ((const float4*)dpw)[5];
    const float4 w6 = ((const float4*)dpw)[6];
    const float4 w7 = ((const float4*)dpw)[7];
    const float bsel = (grp == 0 ? dp1_b : (grp == 1 ? dp2_b : dp3_b))[h];
    const float u1h = U1[(z[n] << 7) + h];
    const float bh = emb2_b[h];

    float a0 = 0.f, a1 = 0.f, a2 = 0.f, a3 = 0.f, a4 = 0.f, a5 = 0.f;

#pragma unroll 2
    for (int i = beg; i < end; i++) {
        const int e = order[i];
        const float4 g = geom[e];
        const float u2v = U2[u2off[e] + h];
        const float4* rp = (const float4*)(rbf_s + (size_t)e * 32);
        const float4 r0 = rp[0], r1 = rp[1], r2 = rp[2], r3 = rp[3];
        const float4 r4 = rp[4], r5 = rp[5], r6 = rp[6], r7 = rp[7];
        float p = bsel;
        p += r0.x * w0.x + r0.y * w0.y + r0.z * w0.z + r0.w * w0.w;
        p += r1.x * w1.x + r1.y * w1.y + r1.z * w1.z + r1.w * w1.w;
        p += r2.x * w2.x + r2.y * w2.y + r2.z * w2.z + r2.w * w2.w;
        p += r3.x * w3.x + r3.y * w3.y + r3.z * w3.z + r3.w * w3.w;
        p += r4.x * w4.x + r4.y * w4.y + r4.z * w4.z + r4.w * w4.w;
        p += r5.x * w5.x + r5.y * w5.y + r5.z * w5.z + r5.w * w5.w;
        p += r6.x * w6.x + r6.y * w6.y + r6.z * w6.z + r6.w * w6.w;
        p += r7.x * w7.x + r7.y * w7.y + r7.z * w7.z + r7.w * w7.w;
        const float c = g.w * (u1h + u2v + bh);
        const float wk = p * c;
        if (grp == 0) {
            a0 += wk;
        } else if (grp == 1) {
            a0 += wk * g.x; a1 += wk * g.y; a2 += wk * g.z;
        } else {
            const float tx = wk * g.x, ty = wk * g.y, tz = wk * g.z;
            a0 += tx * g.x; a1 += tx * g.y; a2 += tx * g.z;
            a3 += ty * g.y; a4 += ty * g.z; a5 += tz * g.z;
        }
    }

    __shared__ float sP[10][128];
    __shared__ float red[128];

    const int idx = n * 128 + h;
    if (grp == 0) {
        sP[0][h] = a0;
        acc_bf[idx] = f2bf(a0);
    } else if (grp == 1) {
        sP[1][h] = a0; sP[2][h] = a1; sP[3][h] = a2;
        acc_bf[NH_TOT + idx] = f2bf(a0);
        acc_bf[2 * NH_TOT + idx] = f2bf(a1);
        acc_bf[3 * NH_TOT + idx] = f2bf(a2);
    } else {
        sP[4][h] = a0; sP[5][h] = a1; sP[6][h] = a2;
        sP[7][h] = a3; sP[8][h] = a4; sP[9][h] = a5;
        acc_bf[4 * NH_TOT + idx] = f2bf(a0);
        acc_bf[5 * NH_TOT + idx] = f2bf(a1);
        acc_bf[6 * NH_TOT + idx] = f2bf(a2);
        acc_bf[7 * NH_TOT + idx] = f2bf(a3);
        acc_bf[8 * NH_TOT + idx] = f2bf(a4);
        acc_bf[9 * NH_TOT + idx] = f2bf(a5);
    }
    __syncthreads();

    float tn = 0.f;
    if (tid < 128) {
        const float aI = sP[0][h];
        const float axv = sP[1][h], ayv = sP[2][h], azv = sP[3][h];
        const float mxx = sP[4][h], mxy = sP[5][h], mxz = sP[6][h];
        const float myy = sP[7][h], myz = sP[8][h], mzz = sP[9][h];
        const float tr3 = (mxx + myy + mzz) * (1.0f / 3.0f);
        const float t00 = aI + mxx - tr3;
        const float t11 = aI + myy - tr3;
        const float t22 = aI + mzz - tr3;
        tn = t00 * t00 + t11 * t11 + t22 * t22 +
             2.0f * (mxy * mxy + azv * azv + mxz * mxz + ayv * ayv + myz * myz + axv * axv);
        red[h] = tn;
    }
    __syncthreads();
    for (int s = 64; s > 0; s >>= 1) { if (tid < s) red[tid] += red[tid + s]; __syncthreads(); }
    const float mu = red[0] * (1.0f / 128.0f);
    __syncthreads();
    float dv = 0.f;
    if (tid < 128) { dv = tn - mu; red[h] = dv * dv; }
    __syncthreads();
    for (int s = 64; s > 0; s >>= 1) { if (tid < s) red[tid] += red[tid + s]; __syncthreads(); }
    const float var = red[0] * (1.0f / 128.0f);
    if (tid < 128)
        nrm_bf[idx] = f2bf(dv * rsqrtf(var + 1e-5f) * init_g[h] + init_b[h]);
}

// ---------------------------------------------------------------------------
// Gate MLP: scal = silu(ls1 @ silu(ls0 @ nrm + b0) + b1), MFMA bf16.
// Block = 16 nodes, 256 threads (4 waves). 256 blocks.
// ---------------------------------------------------------------------------
__global__ __launch_bounds__(256) void k_gates(const unsigned short* __restrict__ nrm_bf,
                                               const unsigned short* __restrict__ wb,
                                               const float* __restrict__ ls0_b,
                                               const float* __restrict__ ls1_b,
                                               float* __restrict__ scal) {
    __shared__ unsigned short h1[16][280];   // 16x256 bf16, stride 280
    const int tid = threadIdx.x;
    const int wave = tid >> 6, lane = tid & 63;
    const int lm = lane & 15, lq = lane >> 4;
    const int m0 = blockIdx.x * 16;

    {   // GEMM1: 16 x 256, K=128; wave covers 64 output cols
        f32x4 acc[4];
#pragma unroll
        for (int j = 0; j < 4; j++) acc[j] = (f32x4){0.f, 0.f, 0.f, 0.f};
        const int n0 = wave * 64;
#pragma unroll
        for (int kc = 0; kc < 128; kc += 32) {
            const bf16x8 af = *(const bf16x8*)(nrm_bf + (size_t)(m0 + lm) * 128 + kc + lq * 8);
#pragma unroll
            for (int sn = 0; sn < 4; sn++) {
                const bf16x8 bfr = *(const bf16x8*)(wb + (size_t)(n0 + sn * 16 + lm) * 128 + kc + lq * 8);
                acc[sn] = __builtin_amdgcn_mfma_f32_16x16x32_bf16(af, bfr, acc[sn], 0, 0, 0);
            }
        }
#pragma unroll
        for (int sn = 0; sn < 4; sn++) {
            const int col = n0 + sn * 16 + lm;
            const float bv = ls0_b[col];
#pragma unroll
            for (int r = 0; r < 4; r++)
                h1[lq * 4 + r][col] = f2bf(silu(acc[sn][r] + bv));
        }
    }
    __syncthreads();
    {   // GEMM2: 16 x 384, K=256; wave covers 96 output cols
        f32x4 acc[6];
#pragma unroll
        for (int j = 0; j < 6; j++) acc[j] = (f32x4){0.f, 0.f, 0.f, 0.f};
        const int n0 = wave * 96;
        const unsigned short* ls1p = wb + 32768;
#pragma unroll 2
        for (int kc = 0; kc < 256; kc += 32) {
            const bf16x8 af = *(const bf16x8*)(&h1[lm][kc + lq * 8]);
#pragma unroll
            for (int sn = 0; sn < 6; sn++) {
                const bf16x8 bfr = *(const bf16x8*)(ls1p + (size_t)(n0 + sn * 16 + lm) * 256 + kc + lq * 8);
                acc[sn] = __builtin_amdgcn_mfma_f32_16x16x32_bf16(af, bfr, acc[sn], 0, 0, 0);
            }
        }
#pragma unroll
        for (int sn = 0; sn < 6; sn++) {
            const int col = n0 + sn * 16 + lm;
            const float bv = ls1_b[col];
#pragma unroll
            for (int r = 0; r < 4; r++)
                scal[(size_t)(m0 + lq * 4 + r) * 384 + col] = silu(acc[sn][r] + bv);
        }
    }
}

// ---------------------------------------------------------------------------
// Fused: 10-plane mix (MFMA, running e0/e1/e2/tr in C-layout regs) + gating
// + LayerNorm(384) + lin + ol1 + ol2. Block = 16 nodes, 256 threads.
// e2 uses ||M - tr/3 I||^2 = sum(diag^2) + 2*sum(off^2) - tr^2/3.
// ---------------------------------------------------------------------------
__global__ __launch_bounds__(256) void k_tailfuse(
    const unsigned short* __restrict__ acc_bf, const unsigned short* __restrict__ wb,
    const float* __restrict__ scal,
    const float* __restrict__ outn_g, const float* __restrict__ outn_b,
    const float* __restrict__ lin_w, const float* __restrict__ lin_b,
    const float* __restrict__ ol1_w, const float* __restrict__ ol1_b,
    const float* __restrict__ ol2_w, const float* __restrict__ ol2_b,
    float* __restrict__ out) {
    const int tid = threadIdx.x;
    const int wave = tid >> 6, lane = tid & 63;
    const int lm = lane & 15, lq = lane >> 4;
    const int n0 = blockIdx.x * 16;

    __shared__ float xs[16][388];
    __shared__ float ss[16][132];
    __shared__ float red1[4][16];
    __shared__ float mu_s[16], rs_s[16];

    // ---- Phase A: 10 GEMMs (16x32 per wave each), running combine ----
    f32x4 e0[2], e1[2], e2[2], trv[2];
#pragma unroll
    for (int sn = 0; sn < 2; sn++) {
        e0[sn] = (f32x4){0.f, 0.f, 0.f, 0.f};
        e1[sn] = (f32x4){0.f, 0.f, 0.f, 0.f};
        e2[sn] = (f32x4){0.f, 0.f, 0.f, 0.f};
        trv[sn] = (f32x4){0.f, 0.f, 0.f, 0.f};
    }
#pragma unroll
    for (int p = 0; p < 10; p++) {
        const unsigned short* A = acc_bf + (size_t)p * NH_TOT;
        const unsigned short* B = wb + (p == 0 ? 131072 : (p < 4 ? 147456 : 163840));
        f32x4 c[2];
        c[0] = (f32x4){0.f, 0.f, 0.f, 0.f};
        c[1] = (f32x4){0.f, 0.f, 0.f, 0.f};
#pragma unroll
        for (int kc = 0; kc < 128; kc += 32) {
            const bf16x8 af = *(const bf16x8*)(A + (size_t)(n0 + lm) * 128 + kc + lq * 8);
#pragma unroll
            for (int sn = 0; sn < 2; sn++) {
                const bf16x8 bfr = *(const bf16x8*)(B + (size_t)(wave * 32 + sn * 16 + lm) * 128 + kc + lq * 8);
                c[sn] = __builtin_amdgcn_mfma_f32_16x16x32_bf16(af, bfr, c[sn], 0, 0, 0);
            }
        }
#pragma unroll
        for (int sn = 0; sn < 2; sn++) {
            if (p == 0)      e0[sn] += c[sn] * c[sn];
            else if (p < 4)  e1[sn] += c[sn] * c[sn];
            else if (p == 4 || p == 7 || p == 9) { e2[sn] += c[sn] * c[sn]; trv[sn] += c[sn]; }
            else             e2[sn] += 2.0f * c[sn] * c[sn];
        }
    }

    // ---- Phase B: gating + LN partial sums ----
    float xv0[2][4], xv1[2][4], xv2[2][4];
    float psum[4] = {0.f, 0.f, 0.f, 0.f};
#pragma unroll
    for (int sn = 0; sn < 2; sn++) {
        const int g = wave * 32 + sn * 16 + lm;
#pragma unroll
        for (int r = 0; r < 4; r++) {
            const int node = lq * 4 + r;
            const float* sp = scal + (size_t)(n0 + node) * 384 + 3 * g;
            const float s0 = sp[0], s1 = sp[1], s2 = sp[2];
            const float a0 = 3.0f * e0[sn][r] * s0 * s0;
            const float a1 = 2.0f * e1[sn][r] * s1 * s1;
            const float tr = trv[sn][r];
            const float a2 = (e2[sn][r] - tr * tr * (1.0f / 3.0f)) * s2 * s2;
            xv0[sn][r] = a0; xv1[sn][r] = a1; xv2[sn][r] = a2;
            psum[r] += a0 + a1 + a2;
        }
    }
#pragma unroll
    for (int r = 0; r < 4; r++)
        for (int s = 8; s > 0; s >>= 1) psum[r] += __shfl_down(psum[r], s, 16);
    if (lm == 0) {
#pragma unroll
        for (int r = 0; r < 4; r++) red1[wave][lq * 4 + r] = psum[r];
    }
    __syncthreads();
    if (tid < 16)
        mu_s[tid] = (red1[0][tid] + red1[1][tid] + red1[2][tid] + red1[3][tid]) * (1.0f / 384.0f);
    __syncthreads();

    float qsum[4] = {0.f, 0.f, 0.f, 0.f};
#pragma unroll
    for (int r = 0; r < 4; r++) {
        const float m = mu_s[lq * 4 + r];
#pragma unroll
        for (int sn = 0; sn < 2; sn++) {
            const float d0 = xv0[sn][r] - m, d1 = xv1[sn][r] - m, d2 = xv2[sn][r] - m;
            qsum[r] += d0 * d0 + d1 * d1 + d2 * d2;
        }
    }
#pragma unroll
    for (int r = 0; r < 4; r++)
        for (int s = 8; s > 0; s >>= 1) qsum[r] += __shfl_down(qsum[r], s, 16);
    __syncthreads();
    if (lm == 0) {
#pragma unroll
        for (int r = 0; r < 4; r++) red1[wave][lq * 4 + r] = qsum[r];
    }
    __syncthreads();
    if (tid < 16)
        rs_s[tid] = rsqrtf((red1[0][tid] + red1[1][tid] + red1[2][tid] + red1[3][tid]) * (1.0f / 384.0f) + 1e-5f);
    __syncthreads();

#pragma unroll
    for (int sn = 0; sn < 2; sn++) {
        const int g = wave * 32 + sn * 16 + lm;
        const float g0 = outn_g[g], g1 = outn_g[128 + g], g2 = outn_g[256 + g];
        const float b0 = outn_b[g], b1 = outn_b[128 + g], b2 = outn_b[256 + g];
#pragma unroll
        for (int r = 0; r < 4; r++) {
            const int node = lq * 4 + r;
            const float m = mu_s[node], rs = rs_s[node];
            xs[node][g]       = (xv0[sn][r] - m) * rs * g0 + b0;
            xs[node][128 + g] = (xv1[sn][r] - m) * rs * g1 + b1;
            xs[node][256 + g] = (xv2[sn][r] - m) * rs * g2 + b2;
        }
    }
    __syncthreads();

    // ---- Phase E: lin (fp32): s1[n][j] = silu(sum_k x[n][k]*lin_w[j][k] + b) ----
    {
        const int j = tid & 127, half = tid >> 7;
        float acc8[8];
        const float lb = lin_b[j];
#pragma unroll
        for (int i = 0; i < 8; i++) acc8[i] = lb;
        const float4* wr = (const float4*)(lin_w + j * 384);
#pragma unroll 2
        for (int k4 = 0; k4 < 96; k4++) {
            const float4 w4 = wr[k4];
#pragma unroll
            for (int i = 0; i < 8; i++) {
                const float4 xv = *(const float4*)&xs[half * 8 + i][k4 * 4];
                acc8[i] += w4.x * xv.x + w4.y * xv.y + w4.z * xv.z + w4.w * xv.w;
            }
        }
#pragma unroll
        for (int i = 0; i < 8; i++) ss[half * 8 + i][j] = silu(acc8[i]);
    }
    __syncthreads();

    // ---- Phase F: ol1 + ol2 ----
    {
        const int o = tid & 63, q = tid >> 6;
        float a4[4];
        const float ob = ol1_b[o];
#pragma unroll
        for (int i = 0; i < 4; i++) a4[i] = ob;
        const float4* o4 = (const float4*)(ol1_w + o * 128);
#pragma unroll 4
        for (int k4 = 0; k4 < 32; k4++) {
            const float4 w4 = o4[k4];
#pragma unroll
            for (int i = 0; i < 4; i++) {
                const float4 sv = *(const float4*)&ss[q * 4 + i][k4 * 4];
                a4[i] += w4.x * sv.x + w4.y * sv.y + w4.z * sv.z + w4.w * sv.w;
            }
        }
        const float w2 = ol2_w[o];
#pragma unroll
        for (int i = 0; i < 4; i++) {
            float v = silu(a4[i]) * w2;
            for (int s = 32; s > 0; s >>= 1) v += __shfl_down(v, s, 64);
            if (o == 0) out[n0 + q * 4 + i] = v + ol2_b[0];
        }
    }
}

// ---------------------------------------------------------------------------
extern "C" void kernel_launch(void* const* d_in, const int* in_sizes, int n_in,
                              void* d_out, int out_size, void* d_ws, size_t ws_size,
                              hipStream_t stream) {
    (void)in_sizes; (void)n_in; (void)out_size; (void)ws_size;
    const float* edge_vec = (const float*)d_in[0];
    const float* emb_w   = (const float*)d_in[1];
    const float* emb2_w  = (const float*)d_in[2];
    const float* emb2_b  = (const float*)d_in[3];
    const float* dp1_w   = (const float*)d_in[4];
    const float* dp1_b   = (const float*)d_in[5];
    const float* dp2_w   = (const float*)d_in[6];
    const float* dp2_b   = (const float*)d_in[7];
    const float* dp3_w   = (const float*)d_in[8];
    const float* dp3_b   = (const float*)d_in[9];
    const float* lt0_w   = (const float*)d_in[10];
    const float* lt1_w   = (const float*)d_in[11];
    const float* lt2_w   = (const float*)d_in[12];
    const float* ls0_w   = (const float*)d_in[13];
    const float* ls0_b   = (const float*)d_in[14];
    const float* ls1_w   = (const float*)d_in[15];
    const float* ls1_b   = (const float*)d_in[16];
    const float* init_g  = (const float*)d_in[17];
    const float* init_b  = (const float*)d_in[18];
    const float* lin_w   = (const float*)d_in[19];
    const float* lin_b   = (const float*)d_in[20];
    const float* outn_g  = (const float*)d_in[21];
    const float* outn_b  = (const float*)d_in[22];
    const float* ol1_w   = (const float*)d_in[23];
    const float* ol1_b   = (const float*)d_in[24];
    const float* ol2_w   = (const float*)d_in[25];
    const float* ol2_b   = (const float*)d_in[26];
    const int* z  = (const int*)d_in[27];
    const int* ei = (const int*)d_in[28];
    float* out = (float*)d_out;

    char* w = (char*)d_ws;
    int*            cnt    = (int*)(w);                       // -> 16384
    int*            cursor = (int*)(w + 16384);               // -> 32768
    int*            off    = (int*)(w + 32768);               // -> 49408
    int*            order  = (int*)(w + 49408);               // -> 311552
    float*          U1     = (float*)(w + 311552);            // -> 377088
    float*          U2     = (float*)(w + 377088);            // -> 442624
    int*            u2off  = (int*)(w + 442624);              // -> 704768
    float4*         geom   = (float4*)(w + 704768);           // -> 1753344
    float*          rbf_s  = (float*)(w + 1753344);           // -> 10141952
    unsigned short* wb     = (unsigned short*)(w + 10141952); // -> 10502400
    unsigned short* nrm_bf = (unsigned short*)(w + 10502400); // -> 11550976
    unsigned short* acc_bf = (unsigned short*)(w + 11550976); // -> 22036736
    float*          scal   = (float*)(w + 22036736);          // -> 28328192

    hipMemsetAsync(w, 0, 32768, stream);  // cnt + cursor
    k_setup<<<dim3(496), dim3(256), 0, stream>>>(emb_w, emb2_w, edge_vec, ei, z,
                                                 ls0_w, ls1_w, lt0_w, lt1_w, lt2_w,
                                                 U1, U2, cnt, u2off, geom, rbf_s, wb);
    k_scan<<<dim3(1), dim3(256), 0, stream>>>(cnt, off);
    k_scatter<<<dim3(256), dim3(256), 0, stream>>>(ei, off, cursor, order);
    k_node<<<dim3(4096), dim3(384), 0, stream>>>(z, off, order, rbf_s, geom, u2off, U1, U2,
                                                 emb2_b, dp1_w, dp1_b, dp2_w, dp2_b, dp3_w, dp3_b,
                                                 init_g, init_b, acc_bf, nrm_bf);
    k_gates<<<dim3(256), dim3(256), 0, stream>>>(nrm_bf, wb, ls0_b, ls1_b, scal);
    k_tailfuse<<<dim3(256), dim3(256), 0, stream>>>(acc_bf, wb, scal, outn_g, outn_b,
                                                    lin_w, lin_b, ol1_w, ol1_b, ol2_w, ol2_b, out);
}

// Round 6
// 245.849 us; speedup vs baseline: 1.2137x; 1.0779x over previous
//
#include <hip/hip_runtime.h>
#include <math.h>

#define NH_TOT 524288   // 4096*128
#define N_ATOM 4096
#define N_EDGE 65536

typedef __attribute__((ext_vector_type(8))) short bf16x8;
typedef __attribute__((ext_vector_type(4))) float f32x4;

__device__ __forceinline__ unsigned short f2bf(float f) {
    unsigned u = __builtin_bit_cast(unsigned, f);
    unsigned r = (u + 0x7fffu + ((u >> 16) & 1u)) >> 16;
    return (unsigned short)r;
}
__device__ __forceinline__ float silu(float v) { return v / (1.0f + expf(-v)); }

// wb layout (bf16 elements):
// ls0@0(32768), ls1@32768(98304), lt0@131072(16384), lt1@147456(16384),
// lt2@163840(16384), dp1@180224(4096), dp2@184320(4096), dp3@188416(4096) end 192512
#define WB_LS1 32768
#define WB_LT0 131072
#define WB_LT1 147456
#define WB_LT2 163840
#define WB_DP  180224

// ---------------------------------------------------------------------------
// Setup: [0,64) U1/U2 tables; [64,320) histogram; [320,508) weight bf16 conv
// ---------------------------------------------------------------------------
__global__ __launch_bounds__(256) void k_setup(
    const float* __restrict__ emb_w, const float* __restrict__ emb2_w,
    const int* __restrict__ ei,
    const float* __restrict__ ls0_w, const float* __restrict__ ls1_w,
    const float* __restrict__ lt0_w, const float* __restrict__ lt1_w,
    const float* __restrict__ lt2_w,
    const float* __restrict__ dp1_w, const float* __restrict__ dp2_w,
    const float* __restrict__ dp3_w,
    float* __restrict__ U1, float* __restrict__ U2,
    int* __restrict__ cnt, unsigned short* __restrict__ wb) {
    const int bx = blockIdx.x, tid = threadIdx.x;
    if (bx < 64) {
        __shared__ float se[2][128];
        const int t = bx * 2 + (tid >> 7), h = tid & 127, half = tid >> 7;
        se[half][h] = emb_w[t * 128 + h];
        __syncthreads();
        float u1 = 0.f, u2 = 0.f;
        const float* row = emb2_w + h * 256;
#pragma unroll 8
        for (int k = 0; k < 128; k++) {
            u1 += se[half][k] * row[k];
            u2 += se[half][k] * row[128 + k];
        }
        U1[t * 128 + h] = u1;
        U2[t * 128 + h] = u2;
    } else if (bx < 320) {
        const int e = (bx - 64) * 256 + tid;
        atomicAdd(&cnt[ei[e]], 1);
    } else {
        const int base = (bx - 320) * 1024 + tid * 4;
        const float* src;
        int off;
        if (base < 32768)       { src = ls0_w; off = 0; }
        else if (base < 131072) { src = ls1_w; off = 32768; }
        else if (base < 147456) { src = lt0_w; off = 131072; }
        else if (base < 163840) { src = lt1_w; off = 147456; }
        else if (base < 180224) { src = lt2_w; off = 163840; }
        else if (base < 184320) { src = dp1_w; off = 180224; }
        else if (base < 188416) { src = dp2_w; off = 184320; }
        else                    { src = dp3_w; off = 188416; }
        const float4 v = *(const float4*)(src + (base - off));
        unsigned short* o = wb + base;
        o[0] = f2bf(v.x); o[1] = f2bf(v.y); o[2] = f2bf(v.z); o[3] = f2bf(v.w);
    }
}

__global__ __launch_bounds__(256) void k_scan(const int* __restrict__ cnt, int* __restrict__ off) {
    __shared__ int s[256];
    const int t = threadIdx.x;
    int loc[16];
    int run = 0;
#pragma unroll
    for (int i = 0; i < 16; i++) { run += cnt[t * 16 + i]; loc[i] = run; }
    s[t] = run;
    __syncthreads();
    for (int d = 1; d < 256; d <<= 1) {
        const int add = (t >= d) ? s[t - d] : 0;
        __syncthreads();
        s[t] += add;
        __syncthreads();
    }
    const int base = s[t] - run;
    if (t == 0) off[0] = 0;
#pragma unroll
    for (int i = 0; i < 16; i++) off[t * 16 + i + 1] = base + loc[i];
}

// ---------------------------------------------------------------------------
// Scatter + edge precompute fused: edge e lands at CSR position pos.
// Writes bf16 rbf row (32, CUT-PREMULTIPLIED like the reference), geom
// {vx,vy,vz,cut}, u2off, all at sorted pos.
// ---------------------------------------------------------------------------
__global__ __launch_bounds__(256) void k_edge(
    const float* __restrict__ edge_vec, const int* __restrict__ ei,
    const int* __restrict__ z, const int* __restrict__ off,
    int* __restrict__ cursor,
    unsigned short* __restrict__ rbf_bf, float4* __restrict__ geom,
    int* __restrict__ u2off) {
    const int e = blockIdx.x * 256 + threadIdx.x;
    const int src = ei[e];
    const int pos = off[src] + atomicAdd(&cursor[src], 1);

    const float evx = edge_vec[3 * e + 0];
    const float evy = edge_vec[3 * e + 1];
    const float evz = edge_vec[3 * e + 2];
    const float d = sqrtf(evx * evx + evy * evy + evz * evz);
    const float inv = 1.0f / d;
    const float cut = (d < 4.5f) ? 0.5f * (cosf(0.6981317007977318f * d) + 1.0f) : 0.0f;
    geom[pos] = make_float4(evx * inv, evy * inv, evz * inv, cut);
    u2off[pos] = z[ei[N_EDGE + e]] << 7;

    const float expd = expf(-1.1111111111111112f * d);
    const float m0 = 0.011108996538242306f;
    const float dm = (1.0f - m0) * (1.0f / 31.0f);
    const float tb = 0.0625f * (1.0f - m0);
    const float beta = 1.0f / (tb * tb);
    unsigned int rb[16];
#pragma unroll
    for (int r = 0; r < 16; r++) {
        const float df0 = expd - (m0 + (float)(2 * r) * dm);
        const float df1 = expd - (m0 + (float)(2 * r + 1) * dm);
        const unsigned lo = f2bf(cut * expf(-beta * df0 * df0));   // cut premultiplied
        const unsigned hi = f2bf(cut * expf(-beta * df1 * df1));   // cut premultiplied
        rb[r] = lo | (hi << 16);
    }
    uint4* dst = (uint4*)(rbf_bf + (size_t)pos * 32);
#pragma unroll
    for (int j = 0; j < 4; j++)
        dst[j] = make_uint4(rb[4 * j], rb[4 * j + 1], rb[4 * j + 2], rb[4 * j + 3]);
}

// ---------------------------------------------------------------------------
// k_node v4 (MFMA): per node, W_k = rbf(E x 32) @ dpk^T(32 x 128) via one
// 16x16x32 MFMA per (M-tile, col-tile, k). Epilogue: c[e,h] multiply (U2
// gather) + 10-plane geometric reduction via shfl_xor. Then tensor_norm + LN.
// 256 threads: wave w owns col-tiles {2w, 2w+1}.
// ---------------------------------------------------------------------------
__global__ __launch_bounds__(256) void k_node(
    const int* __restrict__ z, const int* __restrict__ off,
    const unsigned short* __restrict__ rbf_bf, const float4* __restrict__ geom,
    const int* __restrict__ u2off,
    const float* __restrict__ U1, const float* __restrict__ U2,
    const float* __restrict__ emb2_b,
    const float* __restrict__ dp1_b, const float* __restrict__ dp2_b,
    const float* __restrict__ dp3_b,
    const unsigned short* __restrict__ wb,
    const float* __restrict__ init_g, const float* __restrict__ init_b,
    unsigned short* __restrict__ acc_bf, unsigned short* __restrict__ nrm_bf) {
    const int n = blockIdx.x, tid = threadIdx.x;
    const int wave = tid >> 6, lane = tid & 63, lm = lane & 15, lq = lane >> 4;
    const int beg = off[n];
    const int En = off[n + 1] - beg;
    const int zoff = z[n] << 7;

    const unsigned short* dpw = wb + WB_DP;
    bf16x8 bfr[3][2];
    float u1c[2], bhc[2], bk1[2], bk2[2], bk3[2];
    int cols[2];
#pragma unroll
    for (int t = 0; t < 2; t++) {
        const int col = wave * 32 + t * 16 + lm;
        cols[t] = col;
        u1c[t] = U1[zoff + col];
        bhc[t] = emb2_b[col];
        bk1[t] = dp1_b[col]; bk2[t] = dp2_b[col]; bk3[t] = dp3_b[col];
#pragma unroll
        for (int k = 0; k < 3; k++)
            bfr[k][t] = *(const bf16x8*)(dpw + k * 4096 + col * 32 + lq * 8);
    }

    float part[10][2];
#pragma unroll
    for (int p = 0; p < 10; p++) { part[p][0] = 0.f; part[p][1] = 0.f; }

    for (int mi = 0; mi < En; mi += 16) {
        const int arow = beg + min(mi + lm, En - 1);
        const bf16x8 af = *(const bf16x8*)(rbf_bf + (size_t)arow * 32 + lq * 8);
        f32x4 c[3][2];
#pragma unroll
        for (int k = 0; k < 3; k++)
#pragma unroll
            for (int t = 0; t < 2; t++)
                c[k][t] = __builtin_amdgcn_mfma_f32_16x16x32_bf16(
                    af, bfr[k][t], (f32x4){0.f, 0.f, 0.f, 0.f}, 0, 0, 0);
#pragma unroll
        for (int r = 0; r < 4; r++) {
            const int er = mi + lq * 4 + r;
            const bool valid = er < En;
            const int p = beg + (valid ? er : 0);
            const float4 g = geom[p];
            const int u2o = u2off[p];
#pragma unroll
            for (int t = 0; t < 2; t++) {
                const float u2v = U2[u2o + cols[t]];
                const float cc = valid ? g.w * (u1c[t] + u2v + bhc[t]) : 0.f;
                const float w1 = (c[0][t][r] + bk1[t]) * cc;
                const float w2 = (c[1][t][r] + bk2[t]) * cc;
                const float w3 = (c[2][t][r] + bk3[t]) * cc;
                part[0][t] += w1;
                part[1][t] += w2 * g.x; part[2][t] += w2 * g.y; part[3][t] += w2 * g.z;
                const float tx = w3 * g.x, ty = w3 * g.y;
                part[4][t] += tx * g.x; part[5][t] += tx * g.y; part[6][t] += tx * g.z;
                part[7][t] += ty * g.y; part[8][t] += ty * g.z; part[9][t] += w3 * g.z * g.z;
            }
        }
    }

    __shared__ float sP[10][128];
    __shared__ float red[128];

#pragma unroll
    for (int p = 0; p < 10; p++)
#pragma unroll
        for (int t = 0; t < 2; t++) {
            float v = part[p][t];
            v += __shfl_xor(v, 16, 64);
            v += __shfl_xor(v, 32, 64);
            if (lq == 0) {
                sP[p][cols[t]] = v;
                acc_bf[(size_t)p * NH_TOT + n * 128 + cols[t]] = f2bf(v);
            }
        }
    __syncthreads();

    float tn = 0.f, dv = 0.f;
    if (tid < 128) {
        const int h = tid;
        const float aI = sP[0][h];
        const float axv = sP[1][h], ayv = sP[2][h], azv = sP[3][h];
        const float mxx = sP[4][h], mxy = sP[5][h], mxz = sP[6][h];
        const float myy = sP[7][h], myz = sP[8][h], mzz = sP[9][h];
        const float tr3 = (mxx + myy + mzz) * (1.0f / 3.0f);
        const float t00 = aI + mxx - tr3;
        const float t11 = aI + myy - tr3;
        const float t22 = aI + mzz - tr3;
        tn = t00 * t00 + t11 * t11 + t22 * t22 +
             2.0f * (mxy * mxy + azv * azv + mxz * mxz + ayv * ayv + myz * myz + axv * axv);
        red[tid] = tn;
    }
    __syncthreads();
    for (int s = 64; s > 0; s >>= 1) { if (tid < s) red[tid] += red[tid + s]; __syncthreads(); }
    const float mu = red[0] * (1.0f / 128.0f);
    __syncthreads();
    if (tid < 128) { dv = tn - mu; red[tid] = dv * dv; }
    __syncthreads();
    for (int s = 64; s > 0; s >>= 1) { if (tid < s) red[tid] += red[tid + s]; __syncthreads(); }
    const float var = red[0] * (1.0f / 128.0f);
    if (tid < 128)
        nrm_bf[n * 128 + tid] = f2bf(dv * rsqrtf(var + 1e-5f) * init_g[tid] + init_b[tid]);
}

// ---------------------------------------------------------------------------
// Megatail: gates (2 MFMA GEMMs) + 10-plane mix (MFMA) + combine + LN(384)
// + lin + ol1 + ol2. Block = 8 nodes, 256 threads, 512 blocks.
// ---------------------------------------------------------------------------
__global__ __launch_bounds__(256) void k_megatail(
    const unsigned short* __restrict__ nrm_bf, const unsigned short* __restrict__ acc_bf,
    const unsigned short* __restrict__ wb,
    const float* __restrict__ ls0_b, const float* __restrict__ ls1_b,
    const float* __restrict__ outn_g, const float* __restrict__ outn_b,
    const float* __restrict__ lin_w, const float* __restrict__ lin_b,
    const float* __restrict__ ol1_w, const float* __restrict__ ol1_b,
    const float* __restrict__ ol2_w, const float* __restrict__ ol2_b,
    float* __restrict__ out) {
    const int tid = threadIdx.x, wave = tid >> 6, lane = tid & 63;
    const int lm = lane & 15, lq = lane >> 4;
    const int n0 = blockIdx.x * 8;

    __shared__ unsigned short h1[16][280];
    __shared__ float scal_s[8][388];
    __shared__ float xs[8][388];
    __shared__ float ss[8][132];

    // ---- gates GEMM1: h1 = silu(nrm @ ls0^T + b0), rows 16 (8 valid), N=256
    {
        f32x4 acc[4];
#pragma unroll
        for (int j = 0; j < 4; j++) acc[j] = (f32x4){0.f, 0.f, 0.f, 0.f};
        const int cbase = wave * 64;
#pragma unroll
        for (int kc = 0; kc < 128; kc += 32) {
            const int arow = n0 + min(lm, 7);   // stay in valid node rows
            const bf16x8 af = *(const bf16x8*)(nrm_bf + (size_t)arow * 128 + kc + lq * 8);
#pragma unroll
            for (int sn = 0; sn < 4; sn++) {
                const bf16x8 b = *(const bf16x8*)(wb + (size_t)(cbase + sn * 16 + lm) * 128 + kc + lq * 8);
                acc[sn] = __builtin_amdgcn_mfma_f32_16x16x32_bf16(af, b, acc[sn], 0, 0, 0);
            }
        }
#pragma unroll
        for (int sn = 0; sn < 4; sn++) {
            const int col = cbase + sn * 16 + lm;
            const float bv = ls0_b[col];
#pragma unroll
            for (int r = 0; r < 4; r++)
                h1[lq * 4 + r][col] = f2bf(silu(acc[sn][r] + bv));
        }
    }
    __syncthreads();
    // ---- gates GEMM2: scal = silu(h1 @ ls1^T + b1), N=384, K=256
    {
        f32x4 acc[6];
#pragma unroll
        for (int j = 0; j < 6; j++) acc[j] = (f32x4){0.f, 0.f, 0.f, 0.f};
        const int cbase = wave * 96;
        const unsigned short* ls1p = wb + WB_LS1;
#pragma unroll 2
        for (int kc = 0; kc < 256; kc += 32) {
            const bf16x8 af = *(const bf16x8*)(&h1[lm][kc + lq * 8]);
#pragma unroll
            for (int sn = 0; sn < 6; sn++) {
                const bf16x8 b = *(const bf16x8*)(ls1p + (size_t)(cbase + sn * 16 + lm) * 256 + kc + lq * 8);
                acc[sn] = __builtin_amdgcn_mfma_f32_16x16x32_bf16(af, b, acc[sn], 0, 0, 0);
            }
        }
#pragma unroll
        for (int sn = 0; sn < 6; sn++) {
            const int col = cbase + sn * 16 + lm;
            const float bv = ls1_b[col];
#pragma unroll
            for (int r = 0; r < 4; r++) {
                const int node = lq * 4 + r;
                if (node < 8) scal_s[node][col] = silu(acc[sn][r] + bv);
            }
        }
    }
    __syncthreads();

    // ---- mix: 10 plane GEMMs, running e0/e1/e2/tr in C-layout registers
    f32x4 e0[2], e1[2], e2[2], trv[2];
#pragma unroll
    for (int sn = 0; sn < 2; sn++) {
        e0[sn] = (f32x4){0.f, 0.f, 0.f, 0.f};
        e1[sn] = (f32x4){0.f, 0.f, 0.f, 0.f};
        e2[sn] = (f32x4){0.f, 0.f, 0.f, 0.f};
        trv[sn] = (f32x4){0.f, 0.f, 0.f, 0.f};
    }
#pragma unroll
    for (int p = 0; p < 10; p++) {
        const unsigned short* A = acc_bf + (size_t)p * NH_TOT;
        const unsigned short* B = wb + (p == 0 ? WB_LT0 : (p < 4 ? WB_LT1 : WB_LT2));
        f32x4 c[2];
        c[0] = (f32x4){0.f, 0.f, 0.f, 0.f};
        c[1] = (f32x4){0.f, 0.f, 0.f, 0.f};
#pragma unroll
        for (int kc = 0; kc < 128; kc += 32) {
            const int arow = n0 + min(lm, 7);
            const bf16x8 af = *(const bf16x8*)(A + (size_t)arow * 128 + kc + lq * 8);
#pragma unroll
            for (int sn = 0; sn < 2; sn++) {
                const bf16x8 b = *(const bf16x8*)(B + (size_t)(wave * 32 + sn * 16 + lm) * 128 + kc + lq * 8);
                c[sn] = __builtin_amdgcn_mfma_f32_16x16x32_bf16(af, b, c[sn], 0, 0, 0);
            }
        }
#pragma unroll
        for (int sn = 0; sn < 2; sn++) {
            if (p == 0)      e0[sn] += c[sn] * c[sn];
            else if (p < 4)  e1[sn] += c[sn] * c[sn];
            else if (p == 4 || p == 7 || p == 9) { e2[sn] += c[sn] * c[sn]; trv[sn] += c[sn]; }
            else             e2[sn] += 2.0f * c[sn] * c[sn];
        }
    }

    // ---- combine + gate -> raw xs (only lq<2 lanes own valid nodes)
    if (lq < 2) {
#pragma unroll
        for (int sn = 0; sn < 2; sn++) {
            const int g = wave * 32 + sn * 16 + lm;
#pragma unroll
            for (int r = 0; r < 4; r++) {
                const int node = lq * 4 + r;
                const float s0 = scal_s[node][3 * g + 0];
                const float s1 = scal_s[node][3 * g + 1];
                const float s2 = scal_s[node][3 * g + 2];
                const float a0 = 3.0f * e0[sn][r] * s0 * s0;
                const float a1 = 2.0f * e1[sn][r] * s1 * s1;
                const float tr = trv[sn][r];
                const float a2 = (e2[sn][r] - tr * tr * (1.0f / 3.0f)) * s2 * s2;
                xs[node][g] = a0;
                xs[node][128 + g] = a1;
                xs[node][256 + g] = a2;
            }
        }
    }
    __syncthreads();

    // ---- LN(384): wave w normalizes nodes {2w, 2w+1}
#pragma unroll
    for (int i = 0; i < 2; i++) {
        const int node = wave * 2 + i;
        float v[6];
        float s = 0.f;
#pragma unroll
        for (int j = 0; j < 6; j++) { v[j] = xs[node][lane + 64 * j]; s += v[j]; }
#pragma unroll
        for (int o = 1; o < 64; o <<= 1) s += __shfl_xor(s, o, 64);
        const float mu = s * (1.0f / 384.0f);
        float q = 0.f;
#pragma unroll
        for (int j = 0; j < 6; j++) { v[j] -= mu; q += v[j] * v[j]; }
#pragma unroll
        for (int o = 1; o < 64; o <<= 1) q += __shfl_xor(q, o, 64);
        const float rs = rsqrtf(q * (1.0f / 384.0f) + 1e-5f);
#pragma unroll
        for (int j = 0; j < 6; j++) {
            const int col = lane + 64 * j;
            xs[node][col] = v[j] * rs * outn_g[col] + outn_b[col];
        }
    }
    __syncthreads();

    // ---- lin: s1 = silu(x @ lin^T + b); thread (j, half) does 4 nodes
    {
        const int j = tid & 127, half = tid >> 7;
        float a4[4];
        const float lb = lin_b[j];
#pragma unroll
        for (int i = 0; i < 4; i++) a4[i] = lb;
        const float4* wr = (const float4*)(lin_w + j * 384);
#pragma unroll 2
        for (int k4 = 0; k4 < 96; k4++) {
            const float4 w4 = wr[k4];
#pragma unroll
            for (int i = 0; i < 4; i++) {
                const float4 xv = *(const float4*)&xs[half * 4 + i][k4 * 4];
                a4[i] += w4.x * xv.x + w4.y * xv.y + w4.z * xv.z + w4.w * xv.w;
            }
        }
#pragma unroll
        for (int i = 0; i < 4; i++) ss[half * 4 + i][j] = silu(a4[i]);
    }
    __syncthreads();

    // ---- ol1 + ol2
    {
        const int o = tid & 63, q = tid >> 6;
        float a2v[2];
        const float ob = ol1_b[o];
        a2v[0] = ob; a2v[1] = ob;
        const float4* o4 = (const float4*)(ol1_w + o * 128);
#pragma unroll 4
        for (int k4 = 0; k4 < 32; k4++) {
            const float4 w4 = o4[k4];
#pragma unroll
            for (int i = 0; i < 2; i++) {
                const float4 sv = *(const float4*)&ss[q * 2 + i][k4 * 4];
                a2v[i] += w4.x * sv.x + w4.y * sv.y + w4.z * sv.z + w4.w * sv.w;
            }
        }
        const float w2 = ol2_w[o];
#pragma unroll
        for (int i = 0; i < 2; i++) {
            float v = silu(a2v[i]) * w2;
            for (int s = 32; s > 0; s >>= 1) v += __shfl_down(v, s, 64);
            if (o == 0) out[n0 + q * 2 + i] = v + ol2_b[0];
        }
    }
}

// ---------------------------------------------------------------------------
extern "C" void kernel_launch(void* const* d_in, const int* in_sizes, int n_in,
                              void* d_out, int out_size, void* d_ws, size_t ws_size,
                              hipStream_t stream) {
    (void)in_sizes; (void)n_in; (void)out_size; (void)ws_size;
    const float* edge_vec = (const float*)d_in[0];
    const float* emb_w   = (const float*)d_in[1];
    const float* emb2_w  = (const float*)d_in[2];
    const float* emb2_b  = (const float*)d_in[3];
    const float* dp1_w   = (const float*)d_in[4];
    const float* dp1_b   = (const float*)d_in[5];
    const float* dp2_w   = (const float*)d_in[6];
    const float* dp2_b   = (const float*)d_in[7];
    const float* dp3_w   = (const float*)d_in[8];
    const float* dp3_b   = (const float*)d_in[9];
    const float* lt0_w   = (const float*)d_in[10];
    const float* lt1_w   = (const float*)d_in[11];
    const float* lt2_w   = (const float*)d_in[12];
    const float* ls0_w   = (const float*)d_in[13];
    const float* ls0_b   = (const float*)d_in[14];
    const float* ls1_w   = (const float*)d_in[15];
    const float* ls1_b   = (const float*)d_in[16];
    const float* init_g  = (const float*)d_in[17];
    const float* init_b  = (const float*)d_in[18];
    const float* lin_w   = (const float*)d_in[19];
    const float* lin_b   = (const float*)d_in[20];
    const float* outn_g  = (const float*)d_in[21];
    const float* outn_b  = (const float*)d_in[22];
    const float* ol1_w   = (const float*)d_in[23];
    const float* ol1_b   = (const float*)d_in[24];
    const float* ol2_w   = (const float*)d_in[25];
    const float* ol2_b   = (const float*)d_in[26];
    const int* z  = (const int*)d_in[27];
    const int* ei = (const int*)d_in[28];
    float* out = (float*)d_out;

    char* w = (char*)d_ws;
    int*            cnt    = (int*)(w);                      // -> 16384
    int*            cursor = (int*)(w + 16384);              // -> 32768
    int*            off    = (int*)(w + 32768);              // -> 49408
    unsigned short* wb     = (unsigned short*)(w + 49408);   // 385024 B -> 434432
    float*          U1     = (float*)(w + 434432);           // -> 499968
    float*          U2     = (float*)(w + 499968);           // -> 565504
    int*            u2off  = (int*)(w + 565504);             // -> 827648
    float4*         geom   = (float4*)(w + 827648);          // -> 1876224
    unsigned short* rbf_bf = (unsigned short*)(w + 1876224); // 4 MB -> 6070528
    unsigned short* nrm_bf = (unsigned short*)(w + 6070528); // 1 MB -> 7119104
    unsigned short* acc_bf = (unsigned short*)(w + 7119104); // 10 MB -> 17604864

    hipMemsetAsync(w, 0, 32768, stream);  // cnt + cursor
    k_setup<<<dim3(508), dim3(256), 0, stream>>>(emb_w, emb2_w, ei,
                                                 ls0_w, ls1_w, lt0_w, lt1_w, lt2_w,
                                                 dp1_w, dp2_w, dp3_w,
                                                 U1, U2, cnt, wb);
    k_scan<<<dim3(1), dim3(256), 0, stream>>>(cnt, off);
    k_edge<<<dim3(256), dim3(256), 0, stream>>>(edge_vec, ei, z, off, cursor,
                                                rbf_bf, geom, u2off);
    k_node<<<dim3(4096), dim3(256), 0, stream>>>(z, off, rbf_bf, geom, u2off, U1, U2,
                                                 emb2_b, dp1_b, dp2_b, dp3_b, wb,
                                                 init_g, init_b, acc_bf, nrm_bf);
    k_megatail<<<dim3(512), dim3(256), 0, stream>>>(nrm_bf, acc_bf, wb, ls0_b, ls1_b,
                                                    outn_g, outn_b, lin_w, lin_b,
                                                    ol1_w, ol1_b, ol2_w, ol2_b, out);
}